// Round 1
// baseline (654.351 us; speedup 1.0000x reference)
//
#include <hip/hip_runtime.h>
#include <hip/hip_bf16.h>

#define NN 50000
#define EE 800000
#define ENE (EE + NN)   // edges + self loops
#define CIN 128
#define HIDC 64
#define NHEAD 4

// ---------------------------------------------------------------------------
// CSR build: degree count -> exclusive scan -> scatter (bump allocator).
// After scatter, offs[n] = end of segment n (start of n+1); beg(n)= n? offs[n-1]:0.
// ---------------------------------------------------------------------------

__global__ __launch_bounds__(256)
void deg_kernel(const int* __restrict__ ei, int* __restrict__ deg) {
    int i = blockIdx.x * 256 + threadIdx.x;
    if (i >= ENE) return;
    int d = (i < EE) ? ei[EE + i] : (i - EE);   // dst row of edge_index
    atomicAdd(&deg[d], 1);
}

__global__ __launch_bounds__(1024)
void scan1_kernel(const int* __restrict__ deg, int* __restrict__ offs,
                  int* __restrict__ bsum) {
    __shared__ int s[1024];
    int t = threadIdx.x;
    int i = blockIdx.x * 1024 + t;
    int v = (i < NN) ? deg[i] : 0;
    s[t] = v;
    __syncthreads();
    for (int off = 1; off < 1024; off <<= 1) {
        int a = (t >= off) ? s[t - off] : 0;
        __syncthreads();
        s[t] += a;
        __syncthreads();
    }
    if (i < NN) offs[i] = s[t] - v;   // exclusive
    if (t == 1023) bsum[blockIdx.x] = s[1023];
}

__global__ __launch_bounds__(64)
void scan2_kernel(const int* __restrict__ bsum, int* __restrict__ bpre, int nb) {
    if (threadIdx.x == 0) {
        int run = 0;
        for (int b = 0; b < nb; ++b) { bpre[b] = run; run += bsum[b]; }
    }
}

__global__ __launch_bounds__(256)
void scan3_kernel(int* __restrict__ offs, const int* __restrict__ bpre) {
    int i = blockIdx.x * 256 + threadIdx.x;
    if (i >= NN) return;
    offs[i] += bpre[i >> 10];
}

__global__ __launch_bounds__(256)
void scatter_kernel(const int* __restrict__ ei, int* __restrict__ offs,
                    int* __restrict__ csr_src) {
    int i = blockIdx.x * 256 + threadIdx.x;
    if (i >= ENE) return;
    int d, s;
    if (i < EE) { s = ei[i]; d = ei[EE + i]; }
    else        { s = i - EE; d = i - EE; }
    int p = atomicAdd(&offs[d], 1);
    csr_src[p] = s;
}

// ---------------------------------------------------------------------------
// Generic tiled fp32 GEMM: Y[n, NOUT] = X[n, K] @ W[K, NOUT]
// Block = 256 threads, 32 rows per block. WMODE 1 builds the combined
// [64][128] weight from Wm1 ([0:64] -> cols 0..63, [64:128] -> cols 64..127).
// ---------------------------------------------------------------------------

template<int K, int NOUT, int KT, int WMODE>
__global__ __launch_bounds__(256)
void gemm_kernel(const float* __restrict__ X, const float* __restrict__ W,
                 float* __restrict__ Y, int nrows) {
    constexpr int NJ4 = NOUT / 4;      // float4 col groups
    constexpr int MG  = 256 / NJ4;     // thread row-groups
    constexpr int MR  = 32 / MG;       // rows per thread
    constexpr int KP  = K + 4;         // padded row stride (floats)
    __shared__ float xs[32 * KP];
    __shared__ float wl[KT * NOUT];

    const int tid  = threadIdx.x;
    const int row0 = blockIdx.x * 32;

    for (int idx = tid; idx < 32 * (K / 4); idx += 256) {
        int r = idx / (K / 4), c4 = idx % (K / 4);
        float4 v = make_float4(0.f, 0.f, 0.f, 0.f);
        if (row0 + r < nrows)
            v = *(const float4*)&X[(size_t)(row0 + r) * K + c4 * 4];
        *(float4*)&xs[r * KP + c4 * 4] = v;
    }

    const int jg = tid % NJ4;
    const int mg = tid / NJ4;
    float4 acc[MR];
#pragma unroll
    for (int m = 0; m < MR; ++m) acc[m] = make_float4(0.f, 0.f, 0.f, 0.f);

    for (int kt = 0; kt < K / KT; ++kt) {
        __syncthreads();
        for (int idx = tid; idx < KT * (NOUT / 4); idx += 256) {
            int k = idx / (NOUT / 4), j4 = idx % (NOUT / 4);
            float4 wv;
            if (WMODE == 0) {
                wv = *(const float4*)&W[(size_t)(kt * KT + k) * NOUT + j4 * 4];
            } else {
                int j = j4 * 4;
                if (j < 64) wv = *(const float4*)&W[k * 64 + j];
                else        wv = *(const float4*)&W[(64 + k) * 64 + (j - 64)];
            }
            *(float4*)&wl[k * NOUT + j4 * 4] = wv;
        }
        __syncthreads();

        for (int k4 = 0; k4 < KT / 4; ++k4) {
            float4 wv[4];
#pragma unroll
            for (int r = 0; r < 4; ++r)
                wv[r] = *(const float4*)&wl[(k4 * 4 + r) * NOUT + jg * 4];
#pragma unroll
            for (int m = 0; m < MR; ++m) {
                float4 xv = *(const float4*)&xs[(mg * MR + m) * KP + kt * KT + k4 * 4];
                acc[m].x += xv.x * wv[0].x + xv.y * wv[1].x + xv.z * wv[2].x + xv.w * wv[3].x;
                acc[m].y += xv.x * wv[0].y + xv.y * wv[1].y + xv.z * wv[2].y + xv.w * wv[3].y;
                acc[m].z += xv.x * wv[0].z + xv.y * wv[1].z + xv.z * wv[2].z + xv.w * wv[3].z;
                acc[m].w += xv.x * wv[0].w + xv.y * wv[1].w + xv.z * wv[2].w + xv.w * wv[3].w;
            }
        }
    }

#pragma unroll
    for (int m = 0; m < MR; ++m) {
        int row = row0 + mg * MR + m;
        if (row < nrows)
            *(float4*)&Y[(size_t)row * NOUT + jg * 4] = acc[m];
    }
}

// ---------------------------------------------------------------------------
// Per-node attention scores, layer 1: ss[n,h] = <h1_lin[n,h,:], a_src[h,:]>
// Wave per node; lane reads float4 -> 16-lane groups own one head.
// ---------------------------------------------------------------------------

__global__ __launch_bounds__(256)
void scores1_kernel(const float* __restrict__ hlin, const float* __restrict__ a_src,
                    const float* __restrict__ a_dst, float* __restrict__ ss,
                    float* __restrict__ sd) {
    int lane = threadIdx.x & 63;
    int n = blockIdx.x * 4 + (threadIdx.x >> 6);
    if (n >= NN) return;
    float4 hv = *(const float4*)&hlin[(size_t)n * 256 + lane * 4];
    float4 as = *(const float4*)&a_src[lane * 4];
    float4 ad = *(const float4*)&a_dst[lane * 4];
    float ps = hv.x * as.x + hv.y * as.y + hv.z * as.z + hv.w * as.w;
    float pd = hv.x * ad.x + hv.y * ad.y + hv.z * ad.z + hv.w * ad.w;
#pragma unroll
    for (int m = 1; m < 16; m <<= 1) {
        ps += __shfl_xor(ps, m);
        pd += __shfl_xor(pd, m);
    }
    if ((lane & 15) == 0) {
        ss[n * 4 + (lane >> 4)] = ps;
        sd[n * 4 + (lane >> 4)] = pd;
    }
}

__global__ __launch_bounds__(256)
void scores2_kernel(const float* __restrict__ hlin, const float* __restrict__ a_src,
                    const float* __restrict__ a_dst, float* __restrict__ ss,
                    float* __restrict__ sd) {
    int lane = threadIdx.x & 63;
    int n = blockIdx.x * 4 + (threadIdx.x >> 6);
    if (n >= NN) return;
    float v = hlin[(size_t)n * 64 + lane];
    float ps = v * a_src[lane];
    float pd = v * a_dst[lane];
#pragma unroll
    for (int m = 1; m < 64; m <<= 1) {
        ps += __shfl_xor(ps, m);
        pd += __shfl_xor(pd, m);
    }
    if (lane == 0) { ss[n] = ps; sd[n] = pd; }
}

// ---------------------------------------------------------------------------
// Layer-1 aggregation: wave per dst node, lane = channel. Single pass:
// softmax denominator factors out of the weighted sum. relu(+bias) epilogue.
// ---------------------------------------------------------------------------

__global__ __launch_bounds__(256)
void agg1_kernel(const int* __restrict__ offs, const int* __restrict__ csr_src,
                 const float* __restrict__ ss, const float* __restrict__ sd,
                 const float* __restrict__ hlin, const float* __restrict__ b1,
                 float* __restrict__ h1) {
    int lane = threadIdx.x & 63;
    int n = blockIdx.x * 4 + (threadIdx.x >> 6);
    if (n >= NN) return;
    int beg = (n == 0) ? 0 : offs[n - 1];
    int end = offs[n];
    float4 sdv = *(const float4*)&sd[n * 4];
    float den0 = 0.f, den1 = 0.f, den2 = 0.f, den3 = 0.f;
    float ac0 = 0.f, ac1 = 0.f, ac2 = 0.f, ac3 = 0.f;
    for (int j = beg; j < end; ++j) {
        int s = csr_src[j];
        float4 ssv = *(const float4*)&ss[s * 4];
        float e0 = ssv.x + sdv.x; e0 = e0 > 0.f ? e0 : 0.2f * e0;
        float e1 = ssv.y + sdv.y; e1 = e1 > 0.f ? e1 : 0.2f * e1;
        float e2 = ssv.z + sdv.z; e2 = e2 > 0.f ? e2 : 0.2f * e2;
        float e3 = ssv.w + sdv.w; e3 = e3 > 0.f ? e3 : 0.2f * e3;
        float p0 = __expf(e0), p1 = __expf(e1), p2 = __expf(e2), p3 = __expf(e3);
        den0 += p0; den1 += p1; den2 += p2; den3 += p3;
        const float* hrow = &hlin[(size_t)s * 256];
        ac0 += p0 * hrow[lane];
        ac1 += p1 * hrow[64 + lane];
        ac2 += p2 * hrow[128 + lane];
        ac3 += p3 * hrow[192 + lane];
    }
    float r0 = ac0 / (den0 + 1e-16f) + b1[lane];
    float r1 = ac1 / (den1 + 1e-16f) + b1[64 + lane];
    float r2 = ac2 / (den2 + 1e-16f) + b1[128 + lane];
    float r3 = ac3 / (den3 + 1e-16f) + b1[192 + lane];
    float* orow = &h1[(size_t)n * 256];
    orow[lane]        = r0 > 0.f ? r0 : 0.f;
    orow[64 + lane]   = r1 > 0.f ? r1 : 0.f;
    orow[128 + lane]  = r2 > 0.f ? r2 : 0.f;
    orow[192 + lane]  = r3 > 0.f ? r3 : 0.f;
}

// Layer-2 aggregation (1 head, no relu): h2 = agg + b2
__global__ __launch_bounds__(256)
void agg2_kernel(const int* __restrict__ offs, const int* __restrict__ csr_src,
                 const float* __restrict__ ss, const float* __restrict__ sd,
                 const float* __restrict__ hlin, const float* __restrict__ b2,
                 float* __restrict__ h2) {
    int lane = threadIdx.x & 63;
    int n = blockIdx.x * 4 + (threadIdx.x >> 6);
    if (n >= NN) return;
    int beg = (n == 0) ? 0 : offs[n - 1];
    int end = offs[n];
    float sdn = sd[n];
    float den = 0.f, acc = 0.f;
    for (int j = beg; j < end; ++j) {
        int s = csr_src[j];
        float e = ss[s] + sdn; e = e > 0.f ? e : 0.2f * e;
        float p = __expf(e);
        den += p;
        acc += p * hlin[(size_t)s * 64 + lane];
    }
    h2[(size_t)n * 64 + lane] = acc / (den + 1e-16f) + b2[lane];
}

// ---------------------------------------------------------------------------
// Edge epilogue: z = relu(g_top[p] + g_bot[c] + bm1); out = z @ Wm2 + bm2
// 16 lanes per edge, float4 per lane, shfl-reduce within 16.
// ---------------------------------------------------------------------------

__global__ __launch_bounds__(256)
void edge_kernel(const int* __restrict__ ei, const float* __restrict__ g,
                 const float* __restrict__ bm1, const float* __restrict__ Wm2,
                 const float* __restrict__ bm2, float* __restrict__ out) {
    int l = threadIdx.x & 15;
    int eid = blockIdx.x * 16 + (threadIdx.x >> 4);
    if (eid >= EE) return;
    int p = ei[eid];
    int c = ei[EE + eid];
    float4 a  = *(const float4*)&g[(size_t)p * 128 + l * 4];
    float4 b  = *(const float4*)&g[(size_t)c * 128 + 64 + l * 4];
    float4 bb = *(const float4*)&bm1[l * 4];
    float zx = a.x + b.x + bb.x; zx = zx > 0.f ? zx : 0.f;
    float zy = a.y + b.y + bb.y; zy = zy > 0.f ? zy : 0.f;
    float zz = a.z + b.z + bb.z; zz = zz > 0.f ? zz : 0.f;
    float zw = a.w + b.w + bb.w; zw = zw > 0.f ? zw : 0.f;
    float4 w01 = *(const float4*)&Wm2[l * 8];       // rows 4l, 4l+1
    float4 w23 = *(const float4*)&Wm2[l * 8 + 4];   // rows 4l+2, 4l+3
    float o0 = zx * w01.x + zy * w01.z + zz * w23.x + zw * w23.z;
    float o1 = zx * w01.y + zy * w01.w + zz * w23.y + zw * w23.w;
#pragma unroll
    for (int m = 1; m < 16; m <<= 1) {
        o0 += __shfl_xor(o0, m);
        o1 += __shfl_xor(o1, m);
    }
    if (l == 0)
        *(float2*)&out[(size_t)eid * 2] = make_float2(o0 + bm2[0], o1 + bm2[1]);
}

// ---------------------------------------------------------------------------

extern "C" void kernel_launch(void* const* d_in, const int* in_sizes, int n_in,
                              void* d_out, int out_size, void* d_ws, size_t ws_size,
                              hipStream_t stream) {
    const float* x      = (const float*)d_in[0];
    const int*   ei     = (const int*)d_in[1];
    const float* W1     = (const float*)d_in[2];
    const float* a_src1 = (const float*)d_in[3];
    const float* a_dst1 = (const float*)d_in[4];
    const float* b1     = (const float*)d_in[5];
    const float* W2     = (const float*)d_in[6];
    const float* a_src2 = (const float*)d_in[7];
    const float* a_dst2 = (const float*)d_in[8];
    const float* b2     = (const float*)d_in[9];
    const float* Wm1    = (const float*)d_in[10];
    const float* bm1    = (const float*)d_in[11];
    const float* Wm2    = (const float*)d_in[12];
    const float* bm2    = (const float*)d_in[13];
    float* out = (float*)d_out;

    char* ws = (char*)d_ws;
    size_t off = 0;
    auto alloc = [&](size_t bytes) -> void* {
        void* p = ws + off;
        off += (bytes + 255) & ~(size_t)255;
        return p;
    };
    int*   deg     = (int*)alloc((size_t)NN * 4);
    int*   offs    = (int*)alloc((size_t)NN * 4);
    int*   bsum    = (int*)alloc(64 * 4);
    int*   bpre    = (int*)alloc(64 * 4);
    int*   csr_src = (int*)alloc((size_t)ENE * 4);
    float* ss1     = (float*)alloc((size_t)NN * 4 * 4);
    float* sd1     = (float*)alloc((size_t)NN * 4 * 4);
    float* ss2     = (float*)alloc((size_t)NN * 4);
    float* sd2     = (float*)alloc((size_t)NN * 4);
    float* h1_lin  = (float*)alloc((size_t)NN * 256 * 4);
    float* h1      = (float*)alloc((size_t)NN * 256 * 4);
    float* h2_lin  = (float*)alloc((size_t)NN * 64 * 4);
    float* h2      = (float*)alloc((size_t)NN * 64 * 4);
    float* g       = (float*)alloc((size_t)NN * 128 * 4);
    if (off > ws_size) return;   // insufficient workspace: leave output poisoned

    const int nbScan = (NN + 1023) / 1024;         // 49
    const int gEdges = (ENE + 255) / 256;          // 3321
    const int gNodes4 = (NN + 3) / 4;              // 12500
    const int gRows  = (NN + 31) / 32;             // 1563
    const int gEdge16 = (EE + 15) / 16;            // 50000

    // CSR build
    hipMemsetAsync(deg, 0, (size_t)NN * 4, stream);
    deg_kernel<<<gEdges, 256, 0, stream>>>(ei, deg);
    scan1_kernel<<<nbScan, 1024, 0, stream>>>(deg, offs, bsum);
    scan2_kernel<<<1, 64, 0, stream>>>(bsum, bpre, nbScan);
    scan3_kernel<<<(NN + 255) / 256, 256, 0, stream>>>(offs, bpre);
    scatter_kernel<<<gEdges, 256, 0, stream>>>(ei, offs, csr_src);

    // Layer 1
    gemm_kernel<128, 256, 32, 0><<<gRows, 256, 0, stream>>>(x, W1, h1_lin, NN);
    scores1_kernel<<<gNodes4, 256, 0, stream>>>(h1_lin, a_src1, a_dst1, ss1, sd1);
    agg1_kernel<<<gNodes4, 256, 0, stream>>>(offs, csr_src, ss1, sd1, h1_lin, b1, h1);

    // Layer 2
    gemm_kernel<256, 64, 64, 0><<<gRows, 256, 0, stream>>>(h1, W2, h2_lin, NN);
    scores2_kernel<<<gNodes4, 256, 0, stream>>>(h2_lin, a_src2, a_dst2, ss2, sd2);
    agg2_kernel<<<gNodes4, 256, 0, stream>>>(offs, csr_src, ss2, sd2, h2_lin, b2, h2);

    // Edge MLP (factorized): g = h2 @ [Wm1_top | Wm1_bot], then per-edge epilogue
    gemm_kernel<64, 128, 64, 1><<<gRows, 256, 0, stream>>>(h2, Wm1, g, NN);
    edge_kernel<<<gEdge16, 256, 0, stream>>>(ei, g, bm1, Wm2, bm2, out);
}

// Round 2
// 617.553 us; speedup vs baseline: 1.0596x; 1.0596x over previous
//
#include <hip/hip_runtime.h>
#include <hip/hip_bf16.h>
#include <hip/hip_fp16.h>

#define NN 50000
#define EE 800000
#define ENE (EE + NN)   // edges + self loops
#define CIN 128
#define HIDC 64
#define NHEAD 4

// ---------------------------------------------------------------------------
// CSR build: degree count -> exclusive scan -> scatter (bump allocator).
// After scatter, offs[n] = end of segment n; beg(n) = n ? offs[n-1] : 0.
// ---------------------------------------------------------------------------

__global__ __launch_bounds__(256)
void deg_kernel(const int* __restrict__ ei, int* __restrict__ deg) {
    int i = blockIdx.x * 256 + threadIdx.x;
    if (i >= ENE) return;
    int d = (i < EE) ? ei[EE + i] : (i - EE);   // dst row of edge_index
    atomicAdd(&deg[d], 1);
}

__global__ __launch_bounds__(1024)
void scan1_kernel(const int* __restrict__ deg, int* __restrict__ offs,
                  int* __restrict__ bsum) {
    __shared__ int s[1024];
    int t = threadIdx.x;
    int i = blockIdx.x * 1024 + t;
    int v = (i < NN) ? deg[i] : 0;
    s[t] = v;
    __syncthreads();
    for (int off = 1; off < 1024; off <<= 1) {
        int a = (t >= off) ? s[t - off] : 0;
        __syncthreads();
        s[t] += a;
        __syncthreads();
    }
    if (i < NN) offs[i] = s[t] - v;   // exclusive
    if (t == 1023) bsum[blockIdx.x] = s[1023];
}

__global__ __launch_bounds__(64)
void scan2_kernel(const int* __restrict__ bsum, int* __restrict__ bpre, int nb) {
    if (threadIdx.x == 0) {
        int run = 0;
        for (int b = 0; b < nb; ++b) { bpre[b] = run; run += bsum[b]; }
    }
}

__global__ __launch_bounds__(256)
void scan3_kernel(int* __restrict__ offs, const int* __restrict__ bpre) {
    int i = blockIdx.x * 256 + threadIdx.x;
    if (i >= NN) return;
    offs[i] += bpre[i >> 10];
}

__global__ __launch_bounds__(256)
void scatter_kernel(const int* __restrict__ ei, int* __restrict__ offs,
                    int* __restrict__ csr_src, int* __restrict__ csr_dst) {
    int i = blockIdx.x * 256 + threadIdx.x;
    if (i >= ENE) return;
    int d, s;
    if (i < EE) { s = ei[i]; d = ei[EE + i]; }
    else        { s = i - EE; d = i - EE; }
    int p = atomicAdd(&offs[d], 1);
    csr_src[p] = s;
    csr_dst[p] = d;
}

// ---------------------------------------------------------------------------
// Generic tiled fp32 GEMM: Y[n, NOUT] = X[n, K] @ W[K, NOUT]
// WMODE 1 builds the combined [64][128] weight from Wm1.
// HMODE 0: no half out. 1: permuted [n][c][h] half out (NOUT=256, 4 heads).
//       2: plain [n][NOUT] half out.   WF32: write fp32 Y or not.
// ---------------------------------------------------------------------------

template<int K, int NOUT, int KT, int WMODE, int HMODE, int WF32>
__global__ __launch_bounds__(256)
void gemm_kernel(const float* __restrict__ X, const float* __restrict__ W,
                 float* __restrict__ Y, __half* __restrict__ Yh, int nrows) {
    constexpr int NJ4 = NOUT / 4;      // float4 col groups
    constexpr int MG  = 256 / NJ4;     // thread row-groups
    constexpr int MR  = 32 / MG;       // rows per thread
    constexpr int KP  = K + 4;         // padded row stride (floats)
    __shared__ float xs[32 * KP];
    __shared__ float wl[KT * NOUT];

    const int tid  = threadIdx.x;
    const int row0 = blockIdx.x * 32;

    for (int idx = tid; idx < 32 * (K / 4); idx += 256) {
        int r = idx / (K / 4), c4 = idx % (K / 4);
        float4 v = make_float4(0.f, 0.f, 0.f, 0.f);
        if (row0 + r < nrows)
            v = *(const float4*)&X[(size_t)(row0 + r) * K + c4 * 4];
        *(float4*)&xs[r * KP + c4 * 4] = v;
    }

    const int jg = tid % NJ4;
    const int mg = tid / NJ4;
    float4 acc[MR];
#pragma unroll
    for (int m = 0; m < MR; ++m) acc[m] = make_float4(0.f, 0.f, 0.f, 0.f);

    for (int kt = 0; kt < K / KT; ++kt) {
        __syncthreads();
        for (int idx = tid; idx < KT * (NOUT / 4); idx += 256) {
            int k = idx / (NOUT / 4), j4 = idx % (NOUT / 4);
            float4 wv;
            if (WMODE == 0) {
                wv = *(const float4*)&W[(size_t)(kt * KT + k) * NOUT + j4 * 4];
            } else {
                int j = j4 * 4;
                if (j < 64) wv = *(const float4*)&W[k * 64 + j];
                else        wv = *(const float4*)&W[(64 + k) * 64 + (j - 64)];
            }
            *(float4*)&wl[k * NOUT + j4 * 4] = wv;
        }
        __syncthreads();

        for (int k4 = 0; k4 < KT / 4; ++k4) {
            float4 wv[4];
#pragma unroll
            for (int r = 0; r < 4; ++r)
                wv[r] = *(const float4*)&wl[(k4 * 4 + r) * NOUT + jg * 4];
#pragma unroll
            for (int m = 0; m < MR; ++m) {
                float4 xv = *(const float4*)&xs[(mg * MR + m) * KP + kt * KT + k4 * 4];
                acc[m].x += xv.x * wv[0].x + xv.y * wv[1].x + xv.z * wv[2].x + xv.w * wv[3].x;
                acc[m].y += xv.x * wv[0].y + xv.y * wv[1].y + xv.z * wv[2].y + xv.w * wv[3].y;
                acc[m].z += xv.x * wv[0].z + xv.y * wv[1].z + xv.z * wv[2].z + xv.w * wv[3].z;
                acc[m].w += xv.x * wv[0].w + xv.y * wv[1].w + xv.z * wv[2].w + xv.w * wv[3].w;
            }
        }
    }

#pragma unroll
    for (int m = 0; m < MR; ++m) {
        int row = row0 + mg * MR + m;
        if (row < nrows) {
            if (WF32)
                *(float4*)&Y[(size_t)row * NOUT + jg * 4] = acc[m];
            if (HMODE == 1) {
                // permuted [n][c(64)][h(4)]: j = jg*4+k -> h = j>>6, c = j&63
                const int j0 = jg * 4;
                const int h  = j0 >> 6;
                const int c0 = j0 & 63;
                __half* dst = &Yh[(size_t)row * 256];
                dst[(c0 + 0) * 4 + h] = __float2half(acc[m].x);
                dst[(c0 + 1) * 4 + h] = __float2half(acc[m].y);
                dst[(c0 + 2) * 4 + h] = __float2half(acc[m].z);
                dst[(c0 + 3) * 4 + h] = __float2half(acc[m].w);
            } else if (HMODE == 2) {
                ushort4 hv;
                hv.x = __half_as_ushort(__float2half(acc[m].x));
                hv.y = __half_as_ushort(__float2half(acc[m].y));
                hv.z = __half_as_ushort(__float2half(acc[m].z));
                hv.w = __half_as_ushort(__float2half(acc[m].w));
                *(ushort4*)&Yh[(size_t)row * NOUT + jg * 4] = hv;
            }
        }
    }
}

// ---------------------------------------------------------------------------
// Per-node attention scores.
// ---------------------------------------------------------------------------

__global__ __launch_bounds__(256)
void scores1_kernel(const float* __restrict__ hlin, const float* __restrict__ a_src,
                    const float* __restrict__ a_dst, float* __restrict__ ss,
                    float* __restrict__ sd) {
    int lane = threadIdx.x & 63;
    int n = blockIdx.x * 4 + (threadIdx.x >> 6);
    if (n >= NN) return;
    float4 hv = *(const float4*)&hlin[(size_t)n * 256 + lane * 4];
    float4 as = *(const float4*)&a_src[lane * 4];
    float4 ad = *(const float4*)&a_dst[lane * 4];
    float ps = hv.x * as.x + hv.y * as.y + hv.z * as.z + hv.w * as.w;
    float pd = hv.x * ad.x + hv.y * ad.y + hv.z * ad.z + hv.w * ad.w;
#pragma unroll
    for (int m = 1; m < 16; m <<= 1) {
        ps += __shfl_xor(ps, m);
        pd += __shfl_xor(pd, m);
    }
    if ((lane & 15) == 0) {
        ss[n * 4 + (lane >> 4)] = ps;
        sd[n * 4 + (lane >> 4)] = pd;
    }
}

__global__ __launch_bounds__(256)
void scores2_kernel(const float* __restrict__ hlin, const float* __restrict__ a_src,
                    const float* __restrict__ a_dst, float* __restrict__ ss,
                    float* __restrict__ sd) {
    int lane = threadIdx.x & 63;
    int n = blockIdx.x * 4 + (threadIdx.x >> 6);
    if (n >= NN) return;
    float v = hlin[(size_t)n * 64 + lane];
    float ps = v * a_src[lane];
    float pd = v * a_dst[lane];
#pragma unroll
    for (int m = 1; m < 64; m <<= 1) {
        ps += __shfl_xor(ps, m);
        pd += __shfl_xor(pd, m);
    }
    if (lane == 0) { ss[n] = ps; sd[n] = pd; }
}

// ---------------------------------------------------------------------------
// Per-edge (CSR-slot-ordered) unnormalized softmax weights.
// ---------------------------------------------------------------------------

__global__ __launch_bounds__(256)
void p1_kernel(const int* __restrict__ csr_src, const int* __restrict__ csr_dst,
               const float* __restrict__ ss, const float* __restrict__ sd,
               float4* __restrict__ p1) {
    int j = blockIdx.x * 256 + threadIdx.x;
    if (j >= ENE) return;
    int s = csr_src[j], d = csr_dst[j];
    float4 a = *(const float4*)&ss[s * 4];
    float4 b = *(const float4*)&sd[d * 4];
    float e0 = a.x + b.x; e0 = e0 > 0.f ? e0 : 0.2f * e0;
    float e1 = a.y + b.y; e1 = e1 > 0.f ? e1 : 0.2f * e1;
    float e2 = a.z + b.z; e2 = e2 > 0.f ? e2 : 0.2f * e2;
    float e3 = a.w + b.w; e3 = e3 > 0.f ? e3 : 0.2f * e3;
    p1[j] = make_float4(__expf(e0), __expf(e1), __expf(e2), __expf(e3));
}

__global__ __launch_bounds__(256)
void p2_kernel(const int* __restrict__ csr_src, const int* __restrict__ csr_dst,
               const float* __restrict__ ss, const float* __restrict__ sd,
               float* __restrict__ p2) {
    int j = blockIdx.x * 256 + threadIdx.x;
    if (j >= ENE) return;
    float e = ss[csr_src[j]] + sd[csr_dst[j]];
    e = e > 0.f ? e : 0.2f * e;
    p2[j] = __expf(e);
}

// ---------------------------------------------------------------------------
// Layer-1 aggregation: wave per dst node, lane = channel, half gather.
// h1h layout: [n][c(64)][h(4)] -> one 8B load covers all 4 heads.
// ---------------------------------------------------------------------------

__global__ __launch_bounds__(256)
void agg1_kernel(const int* __restrict__ offs, const int* __restrict__ csr_src,
                 const float4* __restrict__ p1, const __half* __restrict__ h1h,
                 const float* __restrict__ b1, float* __restrict__ h1) {
    int lane = threadIdx.x & 63;
    int n = blockIdx.x * 4 + (threadIdx.x >> 6);
    if (n >= NN) return;
    int beg = (n == 0) ? 0 : offs[n - 1];
    int end = offs[n];
    float den0 = 0.f, den1 = 0.f, den2 = 0.f, den3 = 0.f;
    float ac0 = 0.f, ac1 = 0.f, ac2 = 0.f, ac3 = 0.f;
    for (int j = beg; j < end; ++j) {
        int s = csr_src[j];
        float4 pv = p1[j];
        uint2 hv = *(const uint2*)&h1h[(size_t)s * 256 + lane * 4];
        float2 f01 = __half22float2(*reinterpret_cast<const __half2*>(&hv.x));
        float2 f23 = __half22float2(*reinterpret_cast<const __half2*>(&hv.y));
        den0 += pv.x; den1 += pv.y; den2 += pv.z; den3 += pv.w;
        ac0 += pv.x * f01.x;
        ac1 += pv.y * f01.y;
        ac2 += pv.z * f23.x;
        ac3 += pv.w * f23.y;
    }
    float r0 = ac0 / (den0 + 1e-16f) + b1[lane];
    float r1 = ac1 / (den1 + 1e-16f) + b1[64 + lane];
    float r2 = ac2 / (den2 + 1e-16f) + b1[128 + lane];
    float r3 = ac3 / (den3 + 1e-16f) + b1[192 + lane];
    float* orow = &h1[(size_t)n * 256];
    orow[lane]       = r0 > 0.f ? r0 : 0.f;
    orow[64 + lane]  = r1 > 0.f ? r1 : 0.f;
    orow[128 + lane] = r2 > 0.f ? r2 : 0.f;
    orow[192 + lane] = r3 > 0.f ? r3 : 0.f;
}

// Layer-2 aggregation (1 head, no relu): h2 = agg + b2
__global__ __launch_bounds__(256)
void agg2_kernel(const int* __restrict__ offs, const int* __restrict__ csr_src,
                 const float* __restrict__ p2, const __half* __restrict__ h2h,
                 const float* __restrict__ b2, float* __restrict__ h2) {
    int lane = threadIdx.x & 63;
    int n = blockIdx.x * 4 + (threadIdx.x >> 6);
    if (n >= NN) return;
    int beg = (n == 0) ? 0 : offs[n - 1];
    int end = offs[n];
    float den = 0.f, acc = 0.f;
    for (int j = beg; j < end; ++j) {
        int s = csr_src[j];
        float p = p2[j];
        den += p;
        acc += p * __half2float(h2h[(size_t)s * 64 + lane]);
    }
    h2[(size_t)n * 64 + lane] = acc / (den + 1e-16f) + b2[lane];
}

// ---------------------------------------------------------------------------
// Edge epilogue: z = relu(g_top[p] + g_bot[c] + bm1); out = z @ Wm2 + bm2
// 16 lanes per edge; gh is fp16 [n][128].
// ---------------------------------------------------------------------------

__global__ __launch_bounds__(256)
void edge_kernel(const int* __restrict__ ei, const __half* __restrict__ gh,
                 const float* __restrict__ bm1, const float* __restrict__ Wm2,
                 const float* __restrict__ bm2, float* __restrict__ out) {
    int l = threadIdx.x & 15;
    int eid = blockIdx.x * 16 + (threadIdx.x >> 4);
    if (eid >= EE) return;
    int p = ei[eid];
    int c = ei[EE + eid];
    uint2 av = *(const uint2*)&gh[(size_t)p * 128 + l * 4];
    uint2 bv = *(const uint2*)&gh[(size_t)c * 128 + 64 + l * 4];
    float2 a01 = __half22float2(*reinterpret_cast<const __half2*>(&av.x));
    float2 a23 = __half22float2(*reinterpret_cast<const __half2*>(&av.y));
    float2 b01 = __half22float2(*reinterpret_cast<const __half2*>(&bv.x));
    float2 b23 = __half22float2(*reinterpret_cast<const __half2*>(&bv.y));
    float4 bb = *(const float4*)&bm1[l * 4];
    float zx = a01.x + b01.x + bb.x; zx = zx > 0.f ? zx : 0.f;
    float zy = a01.y + b01.y + bb.y; zy = zy > 0.f ? zy : 0.f;
    float zz = a23.x + b23.x + bb.z; zz = zz > 0.f ? zz : 0.f;
    float zw = a23.y + b23.y + bb.w; zw = zw > 0.f ? zw : 0.f;
    float4 w01 = *(const float4*)&Wm2[l * 8];       // rows 4l, 4l+1
    float4 w23 = *(const float4*)&Wm2[l * 8 + 4];   // rows 4l+2, 4l+3
    float o0 = zx * w01.x + zy * w01.z + zz * w23.x + zw * w23.z;
    float o1 = zx * w01.y + zy * w01.w + zz * w23.y + zw * w23.w;
#pragma unroll
    for (int m = 1; m < 16; m <<= 1) {
        o0 += __shfl_xor(o0, m);
        o1 += __shfl_xor(o1, m);
    }
    if (l == 0)
        *(float2*)&out[(size_t)eid * 2] = make_float2(o0 + bm2[0], o1 + bm2[1]);
}

// ---------------------------------------------------------------------------

extern "C" void kernel_launch(void* const* d_in, const int* in_sizes, int n_in,
                              void* d_out, int out_size, void* d_ws, size_t ws_size,
                              hipStream_t stream) {
    const float* x      = (const float*)d_in[0];
    const int*   ei     = (const int*)d_in[1];
    const float* W1     = (const float*)d_in[2];
    const float* a_src1 = (const float*)d_in[3];
    const float* a_dst1 = (const float*)d_in[4];
    const float* b1     = (const float*)d_in[5];
    const float* W2     = (const float*)d_in[6];
    const float* a_src2 = (const float*)d_in[7];
    const float* a_dst2 = (const float*)d_in[8];
    const float* b2     = (const float*)d_in[9];
    const float* Wm1    = (const float*)d_in[10];
    const float* bm1    = (const float*)d_in[11];
    const float* Wm2    = (const float*)d_in[12];
    const float* bm2    = (const float*)d_in[13];
    float* out = (float*)d_out;

    char* ws = (char*)d_ws;
    size_t off = 0;
    auto alloc = [&](size_t bytes) -> void* {
        void* p = ws + off;
        off += (bytes + 255) & ~(size_t)255;
        return p;
    };
    int*    deg     = (int*)alloc((size_t)NN * 4);
    int*    offs    = (int*)alloc((size_t)NN * 4);
    int*    bsum    = (int*)alloc(64 * 4);
    int*    bpre    = (int*)alloc(64 * 4);
    int*    csr_src = (int*)alloc((size_t)ENE * 4);
    int*    csr_dst = (int*)alloc((size_t)ENE * 4);
    float*  ss1     = (float*)alloc((size_t)NN * 4 * 4);
    float*  sd1     = (float*)alloc((size_t)NN * 4 * 4);
    float*  ss2     = (float*)alloc((size_t)NN * 4);
    float*  sd2     = (float*)alloc((size_t)NN * 4);
    float4* p1      = (float4*)alloc((size_t)ENE * 16);
    float*  p2      = (float*)alloc((size_t)ENE * 4);
    // Region B: h1_lin during layer 1, then reused for layer-2/edge buffers.
    char*   regB    = (char*)alloc((size_t)NN * 256 * 4);       // 51.2 MB
    __half* h1h     = (__half*)alloc((size_t)NN * 256 * 2);     // 25.6 MB
    float*  h1      = (float*)alloc((size_t)NN * 256 * 4);      // 51.2 MB
    if (off > ws_size) return;   // insufficient workspace: leave output poisoned

    float*  h1_lin = (float*)regB;
    float*  h2_lin = (float*)regB;                               // alias (h1_lin dead)
    __half* h2h    = (__half*)(regB + 12800000);
    float*  h2     = (float*)(regB + 19200000);
    __half* gh     = (__half*)(regB + 32000000);

    const int nbScan  = (NN + 1023) / 1024;        // 49
    const int gEdges  = (ENE + 255) / 256;         // 3321
    const int gNodes4 = (NN + 3) / 4;              // 12500
    const int gRows   = (NN + 31) / 32;            // 1563
    const int gEdge16 = (EE + 15) / 16;            // 50000

    // CSR build
    hipMemsetAsync(deg, 0, (size_t)NN * 4, stream);
    deg_kernel<<<gEdges, 256, 0, stream>>>(ei, deg);
    scan1_kernel<<<nbScan, 1024, 0, stream>>>(deg, offs, bsum);
    scan2_kernel<<<1, 64, 0, stream>>>(bsum, bpre, nbScan);
    scan3_kernel<<<(NN + 255) / 256, 256, 0, stream>>>(offs, bpre);
    scatter_kernel<<<gEdges, 256, 0, stream>>>(ei, offs, csr_src, csr_dst);

    // Layer 1
    gemm_kernel<128, 256, 32, 0, 1, 1><<<gRows, 256, 0, stream>>>(x, W1, h1_lin, h1h, NN);
    scores1_kernel<<<gNodes4, 256, 0, stream>>>(h1_lin, a_src1, a_dst1, ss1, sd1);
    p1_kernel<<<gEdges, 256, 0, stream>>>(csr_src, csr_dst, ss1, sd1, p1);
    agg1_kernel<<<gNodes4, 256, 0, stream>>>(offs, csr_src, p1, h1h, b1, h1);

    // Layer 2
    gemm_kernel<256, 64, 64, 0, 2, 1><<<gRows, 256, 0, stream>>>(h1, W2, h2_lin, h2h, NN);
    scores2_kernel<<<gNodes4, 256, 0, stream>>>(h2_lin, a_src2, a_dst2, ss2, sd2);
    p2_kernel<<<gEdges, 256, 0, stream>>>(csr_src, csr_dst, ss2, sd2, p2);
    agg2_kernel<<<gNodes4, 256, 0, stream>>>(offs, csr_src, p2, h2h, b2, h2);

    // Edge MLP (factorized): gh = h2 @ [Wm1_top | Wm1_bot] (fp16), per-edge epilogue
    gemm_kernel<64, 128, 64, 1, 2, 0><<<gRows, 256, 0, stream>>>(h2, Wm1, nullptr, gh, NN);
    edge_kernel<<<gEdge16, 256, 0, stream>>>(ei, gh, bm1, Wm2, bm2, out);
}

// Round 4
// 526.188 us; speedup vs baseline: 1.2436x; 1.1736x over previous
//
#include <hip/hip_runtime.h>
#include <hip/hip_fp16.h>

#define NN 50000
#define EE 800000
#define ENE (EE + NN)   // edges + self loops

typedef _Float16 f16;
typedef __attribute__((ext_vector_type(8))) _Float16 f16x8;
typedef __attribute__((ext_vector_type(4))) _Float16 f16x4;
typedef __attribute__((ext_vector_type(4))) float f32x4;

// ---------------------------------------------------------------------------
// CSR build: degree count -> exclusive scan -> scatter (bump allocator).
// After scatter, offs[n] = end of segment n; beg(n) = n ? offs[n-1] : 0.
// ---------------------------------------------------------------------------

__global__ __launch_bounds__(256)
void deg_kernel(const int* __restrict__ ei, int* __restrict__ deg) {
    int i = blockIdx.x * 256 + threadIdx.x;
    if (i >= ENE) return;
    int d = (i < EE) ? ei[EE + i] : (i - EE);   // dst row of edge_index
    atomicAdd(&deg[d], 1);
}

__global__ __launch_bounds__(1024)
void scan1_kernel(const int* __restrict__ deg, int* __restrict__ offs,
                  int* __restrict__ bsum) {
    __shared__ int s[1024];
    int t = threadIdx.x;
    int i = blockIdx.x * 1024 + t;
    int v = (i < NN) ? deg[i] : 0;
    s[t] = v;
    __syncthreads();
    for (int off = 1; off < 1024; off <<= 1) {
        int a = (t >= off) ? s[t - off] : 0;
        __syncthreads();
        s[t] += a;
        __syncthreads();
    }
    if (i < NN) offs[i] = s[t] - v;   // exclusive
    if (t == 1023) bsum[blockIdx.x] = s[1023];
}

__global__ __launch_bounds__(64)
void scan2_kernel(const int* __restrict__ bsum, int* __restrict__ bpre, int nb) {
    if (threadIdx.x == 0) {
        int run = 0;
        for (int b = 0; b < nb; ++b) { bpre[b] = run; run += bsum[b]; }
    }
}

__global__ __launch_bounds__(256)
void scan3_kernel(int* __restrict__ offs, const int* __restrict__ bpre) {
    int i = blockIdx.x * 256 + threadIdx.x;
    if (i >= NN) return;
    offs[i] += bpre[i >> 10];
}

__global__ __launch_bounds__(256)
void scatter_kernel(const int* __restrict__ ei, int* __restrict__ offs,
                    int* __restrict__ csr_src, int* __restrict__ csr_dst) {
    int i = blockIdx.x * 256 + threadIdx.x;
    if (i >= ENE) return;
    int d, s;
    if (i < EE) { s = ei[i]; d = ei[EE + i]; }
    else        { s = i - EE; d = i - EE; }
    int p = atomicAdd(&offs[d], 1);
    csr_src[p] = s;
    csr_dst[p] = d;
}

// ---------------------------------------------------------------------------
// fp32 -> fp16 casts. x: [NN][128]. Weights: transposed fp16 copies so MFMA
// B-fragments (8 consecutive k per lane) are contiguous 16B loads.
//   W1t[256][128] = W1^T;  W2t[64][256] = W2^T;
//   Wmt[128][64]: Wmt[j][k] = (j<64) ? Wm1[k][j] : Wm1[64+k][j-64]
// ---------------------------------------------------------------------------

__global__ __launch_bounds__(256)
void cast_x_kernel(const float4* __restrict__ x4, f16* __restrict__ xh) {
    int i = blockIdx.x * 256 + threadIdx.x;
    if (i >= NN * 128 / 4) return;
    float4 v = x4[i];
    f16x4 h = { (f16)v.x, (f16)v.y, (f16)v.z, (f16)v.w };
    *(f16x4*)&xh[(size_t)i * 4] = h;
}

__global__ __launch_bounds__(256)
void cast_w_kernel(const float* __restrict__ W1, const float* __restrict__ W2,
                   const float* __restrict__ Wm1, f16* __restrict__ W1t,
                   f16* __restrict__ W2t, f16* __restrict__ Wmt) {
    int idx = blockIdx.x * 256 + threadIdx.x;
    if (idx < 32768) {                       // W1t[j*128+k] = W1[k*256+j]
        int j = idx >> 7, k = idx & 127;
        W1t[idx] = (f16)W1[k * 256 + j];
    } else if (idx < 49152) {                // W2t[j*256+k] = W2[k*64+j]
        int i = idx - 32768;
        int j = i >> 8, k = i & 255;
        W2t[i] = (f16)W2[k * 64 + j];
    } else if (idx < 57344) {                // Wmt[j*64+k]
        int i = idx - 49152;
        int j = i >> 6, k = i & 63;
        float v = (j < 64) ? Wm1[k * 64 + j] : Wm1[(64 + k) * 64 + (j - 64)];
        Wmt[i] = (f16)v;
    }
}

// ---------------------------------------------------------------------------
// MFMA fp16 GEMM: Yh[n, NOUT] = A[n, K] @ Bt^T   (Bt is [NOUT][K] fp16)
// Block = 256 thr = 4 waves; wave (wr,wc) computes 16 rows x 64 cols using
// 4x v_mfma_f32_16x16x32_f16 tiles per k-step. Register-direct fragments
// (A row-major 16B/lane, Bt row-major 16B/lane). Epilogue stages fp16 via
// LDS for coalesced 16B global stores. PERM=1 writes [n][c(64)][h(4)].
// ---------------------------------------------------------------------------

template<int K, int NOUT, int NWR, int NWC, int PERM>
__global__ __launch_bounds__(256)
void mfma_gemm(const f16* __restrict__ A, const f16* __restrict__ Bt,
               f16* __restrict__ Yh, int nrows) {
    constexpr int BROWS = NWR * 16;
    constexpr int LDP = NOUT + 8;            // halves per LDS row (16B pad)
    __shared__ f16 lds[BROWS * LDP];
    const int tid = threadIdx.x;
    const int wid = tid >> 6, lane = tid & 63;
    const int wr = wid / NWC, wc = wid % NWC;
    const int lm = lane & 15, lk = lane >> 4;      // lk in 0..3
    const int row0 = blockIdx.x * BROWS + wr * 16;
    const int col0 = wc * 64;

    int arow = row0 + lm;
    if (arow >= nrows) arow = nrows - 1;           // clamp (partial last block)
    const f16* aptr = A + (size_t)arow * K + lk * 8;

    f32x4 acc[4] = {};
#pragma unroll
    for (int ks = 0; ks < K / 32; ++ks) {
        f16x8 af = *(const f16x8*)(aptr + ks * 32);
#pragma unroll
        for (int ct = 0; ct < 4; ++ct) {
            const f16* bptr = Bt + (size_t)(col0 + ct * 16 + lm) * K + ks * 32 + lk * 8;
            f16x8 bf = *(const f16x8*)bptr;
            acc[ct] = __builtin_amdgcn_mfma_f32_16x16x32_f16(af, bf, acc[ct], 0, 0, 0);
        }
    }

    // C/D frag: col = lane&15, row = (lane>>4)*4 + r  [m89 layout]
#pragma unroll
    for (int ct = 0; ct < 4; ++ct) {
#pragma unroll
        for (int r = 0; r < 4; ++r) {
            int lrow = wr * 16 + lk * 4 + r;       // local row in block
            int j = col0 + ct * 16 + lm;           // global col
            int jj = PERM ? ((j & 63) * 4 + (j >> 6)) : j;
            lds[lrow * LDP + jj] = (f16)acc[ct][r];
        }
    }
    __syncthreads();

    constexpr int CHUNKS = NOUT / 8;               // 16B chunks per row
    for (int idx = tid; idx < BROWS * CHUNKS; idx += 256) {
        int lrow = idx / CHUNKS, ch = idx % CHUNKS;
        int grow = blockIdx.x * BROWS + lrow;
        if (grow < nrows) {
            f16x8 v = *(const f16x8*)&lds[lrow * LDP + ch * 8];
            *(f16x8*)&Yh[(size_t)grow * NOUT + ch * 8] = v;
        }
    }
}

// ---------------------------------------------------------------------------
// Per-node attention scores from fp16 activations.
// scores1: h1h permuted [n][c(64)][h(4)], wave per node, lane = c.
// ---------------------------------------------------------------------------

__global__ __launch_bounds__(256)
void scores1_kernel(const f16* __restrict__ h1h, const float* __restrict__ a_src,
                    const float* __restrict__ a_dst, float* __restrict__ ss,
                    float* __restrict__ sd) {
    int lane = threadIdx.x & 63;
    int n = blockIdx.x * 4 + (threadIdx.x >> 6);
    if (n >= NN) return;
    f16x4 hv = *(const f16x4*)&h1h[(size_t)n * 256 + lane * 4];
    float ps0 = (float)hv[0] * a_src[lane];
    float ps1 = (float)hv[1] * a_src[64 + lane];
    float ps2 = (float)hv[2] * a_src[128 + lane];
    float ps3 = (float)hv[3] * a_src[192 + lane];
    float pd0 = (float)hv[0] * a_dst[lane];
    float pd1 = (float)hv[1] * a_dst[64 + lane];
    float pd2 = (float)hv[2] * a_dst[128 + lane];
    float pd3 = (float)hv[3] * a_dst[192 + lane];
#pragma unroll
    for (int m = 1; m < 64; m <<= 1) {
        ps0 += __shfl_xor(ps0, m); ps1 += __shfl_xor(ps1, m);
        ps2 += __shfl_xor(ps2, m); ps3 += __shfl_xor(ps3, m);
        pd0 += __shfl_xor(pd0, m); pd1 += __shfl_xor(pd1, m);
        pd2 += __shfl_xor(pd2, m); pd3 += __shfl_xor(pd3, m);
    }
    if (lane == 0) {
        *(float4*)&ss[n * 4] = make_float4(ps0, ps1, ps2, ps3);
        *(float4*)&sd[n * 4] = make_float4(pd0, pd1, pd2, pd3);
    }
}

__global__ __launch_bounds__(256)
void scores2_kernel(const f16* __restrict__ h2h, const float* __restrict__ a_src,
                    const float* __restrict__ a_dst, float* __restrict__ ss,
                    float* __restrict__ sd) {
    int lane = threadIdx.x & 63;
    int n = blockIdx.x * 4 + (threadIdx.x >> 6);
    if (n >= NN) return;
    float v = (float)h2h[(size_t)n * 64 + lane];
    float ps = v * a_src[lane];
    float pd = v * a_dst[lane];
#pragma unroll
    for (int m = 1; m < 64; m <<= 1) {
        ps += __shfl_xor(ps, m);
        pd += __shfl_xor(pd, m);
    }
    if (lane == 0) { ss[n] = ps; sd[n] = pd; }
}

// ---------------------------------------------------------------------------
// Per-edge (CSR-slot-ordered) unnormalized softmax weights.
// ---------------------------------------------------------------------------

__global__ __launch_bounds__(256)
void p1_kernel(const int* __restrict__ csr_src, const int* __restrict__ csr_dst,
               const float* __restrict__ ss, const float* __restrict__ sd,
               float4* __restrict__ p1) {
    int j = blockIdx.x * 256 + threadIdx.x;
    if (j >= ENE) return;
    int s = csr_src[j], d = csr_dst[j];
    float4 a = *(const float4*)&ss[s * 4];
    float4 b = *(const float4*)&sd[d * 4];
    float e0 = a.x + b.x; e0 = e0 > 0.f ? e0 : 0.2f * e0;
    float e1 = a.y + b.y; e1 = e1 > 0.f ? e1 : 0.2f * e1;
    float e2 = a.z + b.z; e2 = e2 > 0.f ? e2 : 0.2f * e2;
    float e3 = a.w + b.w; e3 = e3 > 0.f ? e3 : 0.2f * e3;
    p1[j] = make_float4(__expf(e0), __expf(e1), __expf(e2), __expf(e3));
}

__global__ __launch_bounds__(256)
void p2_kernel(const int* __restrict__ csr_src, const int* __restrict__ csr_dst,
               const float* __restrict__ ss, const float* __restrict__ sd,
               float* __restrict__ p2) {
    int j = blockIdx.x * 256 + threadIdx.x;
    if (j >= ENE) return;
    float e = ss[csr_src[j]] + sd[csr_dst[j]];
    e = e > 0.f ? e : 0.2f * e;
    p2[j] = __expf(e);
}

// ---------------------------------------------------------------------------
// Layer-1 aggregation: wave per dst node, lane = channel, fp16 gather.
// h1h layout [n][c(64)][h(4)] -> one 8B load covers all 4 heads.
// Output: fp16 [n][h*64+c] (GEMM2 input).
// ---------------------------------------------------------------------------

__global__ __launch_bounds__(256)
void agg1_kernel(const int* __restrict__ offs, const int* __restrict__ csr_src,
                 const float4* __restrict__ p1, const f16* __restrict__ h1h,
                 const float* __restrict__ b1, f16* __restrict__ h1half) {
    int lane = threadIdx.x & 63;
    int n = blockIdx.x * 4 + (threadIdx.x >> 6);
    if (n >= NN) return;
    int beg = (n == 0) ? 0 : offs[n - 1];
    int end = offs[n];
    float den0 = 0.f, den1 = 0.f, den2 = 0.f, den3 = 0.f;
    float ac0 = 0.f, ac1 = 0.f, ac2 = 0.f, ac3 = 0.f;
    for (int j = beg; j < end; ++j) {
        int s = csr_src[j];
        float4 pv = p1[j];
        f16x4 hv = *(const f16x4*)&h1h[(size_t)s * 256 + lane * 4];
        den0 += pv.x; den1 += pv.y; den2 += pv.z; den3 += pv.w;
        ac0 += pv.x * (float)hv[0];
        ac1 += pv.y * (float)hv[1];
        ac2 += pv.z * (float)hv[2];
        ac3 += pv.w * (float)hv[3];
    }
    float r0 = ac0 / (den0 + 1e-16f) + b1[lane];
    float r1 = ac1 / (den1 + 1e-16f) + b1[64 + lane];
    float r2 = ac2 / (den2 + 1e-16f) + b1[128 + lane];
    float r3 = ac3 / (den3 + 1e-16f) + b1[192 + lane];
    f16* orow = &h1half[(size_t)n * 256];
    orow[lane]       = (f16)(r0 > 0.f ? r0 : 0.f);
    orow[64 + lane]  = (f16)(r1 > 0.f ? r1 : 0.f);
    orow[128 + lane] = (f16)(r2 > 0.f ? r2 : 0.f);
    orow[192 + lane] = (f16)(r3 > 0.f ? r3 : 0.f);
}

// Layer-2 aggregation (1 head, no relu): h2 = agg + b2, fp16 out (GEMM3 input)
__global__ __launch_bounds__(256)
void agg2_kernel(const int* __restrict__ offs, const int* __restrict__ csr_src,
                 const float* __restrict__ p2, const f16* __restrict__ h2linh,
                 const float* __restrict__ b2, f16* __restrict__ h2half) {
    int lane = threadIdx.x & 63;
    int n = blockIdx.x * 4 + (threadIdx.x >> 6);
    if (n >= NN) return;
    int beg = (n == 0) ? 0 : offs[n - 1];
    int end = offs[n];
    float den = 0.f, acc = 0.f;
    for (int j = beg; j < end; ++j) {
        int s = csr_src[j];
        float p = p2[j];
        den += p;
        acc += p * (float)h2linh[(size_t)s * 64 + lane];
    }
    h2half[(size_t)n * 64 + lane] = (f16)(acc / (den + 1e-16f) + b2[lane]);
}

// ---------------------------------------------------------------------------
// Edge epilogue: z = relu(g_top[p] + g_bot[c] + bm1); out = z @ Wm2 + bm2
// 16 lanes per edge; gh is fp16 [n][128].
// ---------------------------------------------------------------------------

__global__ __launch_bounds__(256)
void edge_kernel(const int* __restrict__ ei, const f16* __restrict__ gh,
                 const float* __restrict__ bm1, const float* __restrict__ Wm2,
                 const float* __restrict__ bm2, float* __restrict__ out) {
    int l = threadIdx.x & 15;
    int eid = blockIdx.x * 16 + (threadIdx.x >> 4);
    if (eid >= EE) return;
    int p = ei[eid];
    int c = ei[EE + eid];
    f16x4 av = *(const f16x4*)&gh[(size_t)p * 128 + l * 4];
    f16x4 bv = *(const f16x4*)&gh[(size_t)c * 128 + 64 + l * 4];
    float4 bb = *(const float4*)&bm1[l * 4];
    float zx = (float)av[0] + (float)bv[0] + bb.x; zx = zx > 0.f ? zx : 0.f;
    float zy = (float)av[1] + (float)bv[1] + bb.y; zy = zy > 0.f ? zy : 0.f;
    float zz = (float)av[2] + (float)bv[2] + bb.z; zz = zz > 0.f ? zz : 0.f;
    float zw = (float)av[3] + (float)bv[3] + bb.w; zw = zw > 0.f ? zw : 0.f;
    float4 w01 = *(const float4*)&Wm2[l * 8];       // rows 4l, 4l+1
    float4 w23 = *(const float4*)&Wm2[l * 8 + 4];   // rows 4l+2, 4l+3
    float o0 = zx * w01.x + zy * w01.z + zz * w23.x + zw * w23.z;
    float o1 = zx * w01.y + zy * w01.w + zz * w23.y + zw * w23.w;
#pragma unroll
    for (int m = 1; m < 16; m <<= 1) {
        o0 += __shfl_xor(o0, m);
        o1 += __shfl_xor(o1, m);
    }
    if (l == 0)
        *(float2*)&out[(size_t)eid * 2] = make_float2(o0 + bm2[0], o1 + bm2[1]);
}

// ---------------------------------------------------------------------------

extern "C" void kernel_launch(void* const* d_in, const int* in_sizes, int n_in,
                              void* d_out, int out_size, void* d_ws, size_t ws_size,
                              hipStream_t stream) {
    const float* x      = (const float*)d_in[0];
    const int*   ei     = (const int*)d_in[1];
    const float* W1     = (const float*)d_in[2];
    const float* a_src1 = (const float*)d_in[3];
    const float* a_dst1 = (const float*)d_in[4];
    const float* b1     = (const float*)d_in[5];
    const float* W2     = (const float*)d_in[6];
    const float* a_src2 = (const float*)d_in[7];
    const float* a_dst2 = (const float*)d_in[8];
    const float* b2     = (const float*)d_in[9];
    const float* Wm1    = (const float*)d_in[10];
    const float* bm1    = (const float*)d_in[11];
    const float* Wm2    = (const float*)d_in[12];
    const float* bm2    = (const float*)d_in[13];
    float* out = (float*)d_out;

    char* ws = (char*)d_ws;
    size_t off = 0;
    auto alloc = [&](size_t bytes) -> void* {
        void* p = ws + off;
        off += (bytes + 255) & ~(size_t)255;
        return p;
    };
    int*    deg     = (int*)alloc((size_t)NN * 4);
    int*    offs    = (int*)alloc((size_t)NN * 4);
    int*    bsum    = (int*)alloc(64 * 4);
    int*    bpre    = (int*)alloc(64 * 4);
    int*    csr_src = (int*)alloc((size_t)ENE * 4);
    int*    csr_dst = (int*)alloc((size_t)ENE * 4);
    float*  ss1     = (float*)alloc((size_t)NN * 4 * 4);
    float*  sd1     = (float*)alloc((size_t)NN * 4 * 4);
    float*  ss2     = (float*)alloc((size_t)NN * 4);
    float*  sd2     = (float*)alloc((size_t)NN * 4);
    float4* p1      = (float4*)alloc((size_t)ENE * 16);
    float*  p2      = (float*)alloc((size_t)ENE * 4);
    f16*    xh      = (f16*)alloc((size_t)NN * 128 * 2);
    f16*    W1t     = (f16*)alloc((size_t)256 * 128 * 2);
    f16*    W2t     = (f16*)alloc((size_t)64 * 256 * 2);
    f16*    Wmt     = (f16*)alloc((size_t)128 * 64 * 2);
    f16*    h1h     = (f16*)alloc((size_t)NN * 256 * 2);   // permuted [n][c][h]
    f16*    h1half  = (f16*)alloc((size_t)NN * 256 * 2);   // [n][h*64+c]
    f16*    h2linh  = (f16*)alloc((size_t)NN * 64 * 2);
    f16*    h2half  = (f16*)alloc((size_t)NN * 64 * 2);
    f16*    gh      = (f16*)alloc((size_t)NN * 128 * 2);
    if (off > ws_size) return;   // insufficient workspace: leave output poisoned

    const int nbScan  = (NN + 1023) / 1024;        // 49
    const int gEdges  = (ENE + 255) / 256;         // 3321
    const int gNodes4 = (NN + 3) / 4;              // 12500
    const int gEdge16 = (EE + 15) / 16;            // 50000

    // Casts (independent of CSR)
    cast_x_kernel<<<(NN * 128 / 4 + 255) / 256, 256, 0, stream>>>((const float4*)x, xh);
    cast_w_kernel<<<(57344 + 255) / 256, 256, 0, stream>>>(W1, W2, Wm1, W1t, W2t, Wmt);

    // CSR build
    hipMemsetAsync(deg, 0, (size_t)NN * 4, stream);
    deg_kernel<<<gEdges, 256, 0, stream>>>(ei, deg);
    scan1_kernel<<<nbScan, 1024, 0, stream>>>(deg, offs, bsum);
    scan2_kernel<<<1, 64, 0, stream>>>(bsum, bpre, nbScan);
    scan3_kernel<<<(NN + 255) / 256, 256, 0, stream>>>(offs, bpre);
    scatter_kernel<<<gEdges, 256, 0, stream>>>(ei, offs, csr_src, csr_dst);

    // Layer 1: h1h = fp16( xh @ W1 ), permuted epilogue
    mfma_gemm<128, 256, 1, 4, 1><<<NN / 16, 256, 0, stream>>>(xh, W1t, h1h, NN);
    scores1_kernel<<<gNodes4, 256, 0, stream>>>(h1h, a_src1, a_dst1, ss1, sd1);
    p1_kernel<<<gEdges, 256, 0, stream>>>(csr_src, csr_dst, ss1, sd1, p1);
    agg1_kernel<<<gNodes4, 256, 0, stream>>>(offs, csr_src, p1, h1h, b1, h1half);

    // Layer 2
    mfma_gemm<256, 64, 4, 1, 0><<<(NN + 63) / 64, 256, 0, stream>>>(h1half, W2t, h2linh, NN);
    scores2_kernel<<<gNodes4, 256, 0, stream>>>(h2linh, a_src2, a_dst2, ss2, sd2);
    p2_kernel<<<gEdges, 256, 0, stream>>>(csr_src, csr_dst, ss2, sd2, p2);
    agg2_kernel<<<gNodes4, 256, 0, stream>>>(offs, csr_src, p2, h2linh, b2, h2half);

    // Edge MLP (factorized): gh = h2 @ [Wm1_top | Wm1_bot], per-edge epilogue
    mfma_gemm<64, 128, 2, 2, 0><<<(NN + 31) / 32, 256, 0, stream>>>(h2half, Wmt, gh, NN);
    edge_kernel<<<gEdge16, 256, 0, stream>>>(ei, gh, bm1, Wm2, bm2, out);
}

// Round 5
// 450.087 us; speedup vs baseline: 1.4538x; 1.1691x over previous
//
#include <hip/hip_runtime.h>
#include <hip/hip_fp16.h>

#define NN 50000
#define EE 800000
#define ENE (EE + NN)   // edges + self loops

typedef _Float16 f16;
typedef __attribute__((ext_vector_type(8))) _Float16 f16x8;
typedef __attribute__((ext_vector_type(4))) _Float16 f16x4;
typedef __attribute__((ext_vector_type(4))) float f32x4;

// ---------------------------------------------------------------------------
// CSR build: degree count -> exclusive scan -> scatter (bump allocator).
// After scatter, offs[n] = end of segment n; beg(n) = n ? offs[n-1] : 0.
// ---------------------------------------------------------------------------

__global__ __launch_bounds__(256)
void deg_kernel(const int* __restrict__ ei, int* __restrict__ deg) {
    int i = blockIdx.x * 256 + threadIdx.x;
    if (i >= ENE) return;
    int d = (i < EE) ? ei[EE + i] : (i - EE);   // dst row of edge_index
    atomicAdd(&deg[d], 1);
}

__global__ __launch_bounds__(1024)
void scan1_kernel(const int* __restrict__ deg, int* __restrict__ offs,
                  int* __restrict__ bsum) {
    __shared__ int s[1024];
    int t = threadIdx.x;
    int i = blockIdx.x * 1024 + t;
    int v = (i < NN) ? deg[i] : 0;
    s[t] = v;
    __syncthreads();
    for (int off = 1; off < 1024; off <<= 1) {
        int a = (t >= off) ? s[t - off] : 0;
        __syncthreads();
        s[t] += a;
        __syncthreads();
    }
    if (i < NN) offs[i] = s[t] - v;   // exclusive
    if (t == 1023) bsum[blockIdx.x] = s[1023];
}

__global__ __launch_bounds__(64)
void scan2_kernel(const int* __restrict__ bsum, int* __restrict__ bpre, int nb) {
    if (threadIdx.x == 0) {
        int run = 0;
        for (int b = 0; b < nb; ++b) { bpre[b] = run; run += bsum[b]; }
    }
}

__global__ __launch_bounds__(256)
void scan3_kernel(int* __restrict__ offs, const int* __restrict__ bpre) {
    int i = blockIdx.x * 256 + threadIdx.x;
    if (i >= NN) return;
    offs[i] += bpre[i >> 10];
}

__global__ __launch_bounds__(256)
void scatter_kernel(const int* __restrict__ ei, int* __restrict__ offs,
                    int* __restrict__ csr_src, int* __restrict__ csr_dst) {
    int i = blockIdx.x * 256 + threadIdx.x;
    if (i >= ENE) return;
    int d, s;
    if (i < EE) { s = ei[i]; d = ei[EE + i]; }
    else        { s = i - EE; d = i - EE; }
    int p = atomicAdd(&offs[d], 1);
    csr_src[p] = s;
    csr_dst[p] = d;
}

// ---------------------------------------------------------------------------
// fp32 -> fp16 casts. x: [NN][128]. Weights: transposed fp16 copies so MFMA
// B-fragments (8 consecutive k per lane) are contiguous 16B loads.
// ---------------------------------------------------------------------------

__global__ __launch_bounds__(256)
void cast_x_kernel(const float4* __restrict__ x4, f16* __restrict__ xh) {
    int i = blockIdx.x * 256 + threadIdx.x;
    if (i >= NN * 128 / 4) return;
    float4 v = x4[i];
    f16x4 h = { (f16)v.x, (f16)v.y, (f16)v.z, (f16)v.w };
    *(f16x4*)&xh[(size_t)i * 4] = h;
}

__global__ __launch_bounds__(256)
void cast_w_kernel(const float* __restrict__ W1, const float* __restrict__ W2,
                   const float* __restrict__ Wm1, f16* __restrict__ W1t,
                   f16* __restrict__ W2t, f16* __restrict__ Wmt) {
    int idx = blockIdx.x * 256 + threadIdx.x;
    if (idx < 32768) {                       // W1t[j*128+k] = W1[k*256+j]
        int j = idx >> 7, k = idx & 127;
        W1t[idx] = (f16)W1[k * 256 + j];
    } else if (idx < 49152) {                // W2t[j*256+k] = W2[k*64+j]
        int i = idx - 32768;
        int j = i >> 8, k = i & 255;
        W2t[i] = (f16)W2[k * 64 + j];
    } else if (idx < 57344) {                // Wmt[j*64+k]
        int i = idx - 49152;
        int j = i >> 6, k = i & 63;
        float v = (j < 64) ? Wm1[k * 64 + j] : Wm1[(64 + k) * 64 + (j - 64)];
        Wmt[i] = (f16)v;
    }
}

// ---------------------------------------------------------------------------
// MFMA fp16 GEMM: Yh[n, NOUT] = A[n, K] @ Bt^T   (Bt is [NOUT][K] fp16)
// Block = 256 thr = 4 waves; wave (wr,wc) computes 16 rows x 64 cols using
// 4x v_mfma_f32_16x16x32_f16 tiles per k-step. PERM=1 writes [n][c(64)][h(4)].
// ---------------------------------------------------------------------------

template<int K, int NOUT, int NWR, int NWC, int PERM>
__global__ __launch_bounds__(256)
void mfma_gemm(const f16* __restrict__ A, const f16* __restrict__ Bt,
               f16* __restrict__ Yh, int nrows) {
    constexpr int BROWS = NWR * 16;
    constexpr int LDP = NOUT + 8;            // halves per LDS row (16B pad)
    __shared__ f16 lds[BROWS * LDP];
    const int tid = threadIdx.x;
    const int wid = tid >> 6, lane = tid & 63;
    const int wr = wid / NWC, wc = wid % NWC;
    const int lm = lane & 15, lk = lane >> 4;      // lk in 0..3
    const int row0 = blockIdx.x * BROWS + wr * 16;
    const int col0 = wc * 64;

    int arow = row0 + lm;
    if (arow >= nrows) arow = nrows - 1;           // clamp (partial last block)
    const f16* aptr = A + (size_t)arow * K + lk * 8;

    f32x4 acc[4] = {};
#pragma unroll
    for (int ks = 0; ks < K / 32; ++ks) {
        f16x8 af = *(const f16x8*)(aptr + ks * 32);
#pragma unroll
        for (int ct = 0; ct < 4; ++ct) {
            const f16* bptr = Bt + (size_t)(col0 + ct * 16 + lm) * K + ks * 32 + lk * 8;
            f16x8 bf = *(const f16x8*)bptr;
            acc[ct] = __builtin_amdgcn_mfma_f32_16x16x32_f16(af, bf, acc[ct], 0, 0, 0);
        }
    }

    // C/D frag: col = lane&15, row = (lane>>4)*4 + r  [m89 layout]
#pragma unroll
    for (int ct = 0; ct < 4; ++ct) {
#pragma unroll
        for (int r = 0; r < 4; ++r) {
            int lrow = wr * 16 + lk * 4 + r;       // local row in block
            int j = col0 + ct * 16 + lm;           // global col
            int jj = PERM ? ((j & 63) * 4 + (j >> 6)) : j;
            lds[lrow * LDP + jj] = (f16)acc[ct][r];
        }
    }
    __syncthreads();

    constexpr int CHUNKS = NOUT / 8;               // 16B chunks per row
    for (int idx = tid; idx < BROWS * CHUNKS; idx += 256) {
        int lrow = idx / CHUNKS, ch = idx % CHUNKS;
        int grow = blockIdx.x * BROWS + lrow;
        if (grow < nrows) {
            f16x8 v = *(const f16x8*)&lds[lrow * LDP + ch * 8];
            *(f16x8*)&Yh[(size_t)grow * NOUT + ch * 8] = v;
        }
    }
}

// ---------------------------------------------------------------------------
// Per-node attention scores from fp16 activations.
// ---------------------------------------------------------------------------

__global__ __launch_bounds__(256)
void scores1_kernel(const f16* __restrict__ h1h, const float* __restrict__ a_src,
                    const float* __restrict__ a_dst, float* __restrict__ ss,
                    float* __restrict__ sd) {
    int lane = threadIdx.x & 63;
    int n = blockIdx.x * 4 + (threadIdx.x >> 6);
    if (n >= NN) return;
    f16x4 hv = *(const f16x4*)&h1h[(size_t)n * 256 + lane * 4];
    float ps0 = (float)hv[0] * a_src[lane];
    float ps1 = (float)hv[1] * a_src[64 + lane];
    float ps2 = (float)hv[2] * a_src[128 + lane];
    float ps3 = (float)hv[3] * a_src[192 + lane];
    float pd0 = (float)hv[0] * a_dst[lane];
    float pd1 = (float)hv[1] * a_dst[64 + lane];
    float pd2 = (float)hv[2] * a_dst[128 + lane];
    float pd3 = (float)hv[3] * a_dst[192 + lane];
#pragma unroll
    for (int m = 1; m < 64; m <<= 1) {
        ps0 += __shfl_xor(ps0, m); ps1 += __shfl_xor(ps1, m);
        ps2 += __shfl_xor(ps2, m); ps3 += __shfl_xor(ps3, m);
        pd0 += __shfl_xor(pd0, m); pd1 += __shfl_xor(pd1, m);
        pd2 += __shfl_xor(pd2, m); pd3 += __shfl_xor(pd3, m);
    }
    if (lane == 0) {
        *(float4*)&ss[n * 4] = make_float4(ps0, ps1, ps2, ps3);
        *(float4*)&sd[n * 4] = make_float4(pd0, pd1, pd2, pd3);
    }
}

__global__ __launch_bounds__(256)
void scores2_kernel(const f16* __restrict__ h2h, const float* __restrict__ a_src,
                    const float* __restrict__ a_dst, float* __restrict__ ss,
                    float* __restrict__ sd) {
    int lane = threadIdx.x & 63;
    int n = blockIdx.x * 4 + (threadIdx.x >> 6);
    if (n >= NN) return;
    float v = (float)h2h[(size_t)n * 64 + lane];
    float ps = v * a_src[lane];
    float pd = v * a_dst[lane];
#pragma unroll
    for (int m = 1; m < 64; m <<= 1) {
        ps += __shfl_xor(ps, m);
        pd += __shfl_xor(pd, m);
    }
    if (lane == 0) { ss[n] = ps; sd[n] = pd; }
}

// ---------------------------------------------------------------------------
// Per-edge (CSR-slot-ordered) unnormalized softmax weights.
// ---------------------------------------------------------------------------

__global__ __launch_bounds__(256)
void p1_kernel(const int* __restrict__ csr_src, const int* __restrict__ csr_dst,
               const float* __restrict__ ss, const float* __restrict__ sd,
               float4* __restrict__ p1) {
    int j = blockIdx.x * 256 + threadIdx.x;
    if (j >= ENE) return;
    int s = csr_src[j], d = csr_dst[j];
    float4 a = *(const float4*)&ss[s * 4];
    float4 b = *(const float4*)&sd[d * 4];
    float e0 = a.x + b.x; e0 = e0 > 0.f ? e0 : 0.2f * e0;
    float e1 = a.y + b.y; e1 = e1 > 0.f ? e1 : 0.2f * e1;
    float e2 = a.z + b.z; e2 = e2 > 0.f ? e2 : 0.2f * e2;
    float e3 = a.w + b.w; e3 = e3 > 0.f ? e3 : 0.2f * e3;
    p1[j] = make_float4(__expf(e0), __expf(e1), __expf(e2), __expf(e3));
}

__global__ __launch_bounds__(256)
void p2_kernel(const int* __restrict__ csr_src, const int* __restrict__ csr_dst,
               const float* __restrict__ ss, const float* __restrict__ sd,
               float* __restrict__ p2) {
    int j = blockIdx.x * 256 + threadIdx.x;
    if (j >= ENE) return;
    float e = ss[csr_src[j]] + sd[csr_dst[j]];
    e = e > 0.f ? e : 0.2f * e;
    p2[j] = __expf(e);
}

// ---------------------------------------------------------------------------
// Layer-1 aggregation: wave per dst node, lane = channel, fp16 gather.
// 4x manual unroll: batch independent index loads, then issue 4 independent
// row-gathers before any use -> MLP ~4-8 instead of ~1 (latency-bound fix).
// ---------------------------------------------------------------------------

__global__ __launch_bounds__(256)
void agg1_kernel(const int* __restrict__ offs, const int* __restrict__ csr_src,
                 const float4* __restrict__ p1, const f16* __restrict__ h1h,
                 const float* __restrict__ b1, f16* __restrict__ h1half) {
    int lane = threadIdx.x & 63;
    int n = blockIdx.x * 4 + (threadIdx.x >> 6);
    if (n >= NN) return;
    int beg = (n == 0) ? 0 : offs[n - 1];
    int end = offs[n];
    float den0 = 0.f, den1 = 0.f, den2 = 0.f, den3 = 0.f;
    float ac0 = 0.f, ac1 = 0.f, ac2 = 0.f, ac3 = 0.f;
    int j = beg;
    for (; j + 4 <= end; j += 4) {
        int s0 = csr_src[j + 0];
        int s1 = csr_src[j + 1];
        int s2 = csr_src[j + 2];
        int s3 = csr_src[j + 3];
        float4 q0 = p1[j + 0];
        float4 q1 = p1[j + 1];
        float4 q2 = p1[j + 2];
        float4 q3 = p1[j + 3];
        f16x4 h0 = *(const f16x4*)&h1h[(size_t)s0 * 256 + lane * 4];
        f16x4 h1 = *(const f16x4*)&h1h[(size_t)s1 * 256 + lane * 4];
        f16x4 h2 = *(const f16x4*)&h1h[(size_t)s2 * 256 + lane * 4];
        f16x4 h3 = *(const f16x4*)&h1h[(size_t)s3 * 256 + lane * 4];
        den0 += (q0.x + q1.x) + (q2.x + q3.x);
        den1 += (q0.y + q1.y) + (q2.y + q3.y);
        den2 += (q0.z + q1.z) + (q2.z + q3.z);
        den3 += (q0.w + q1.w) + (q2.w + q3.w);
        ac0 += q0.x * (float)h0[0] + q1.x * (float)h1[0]
             + q2.x * (float)h2[0] + q3.x * (float)h3[0];
        ac1 += q0.y * (float)h0[1] + q1.y * (float)h1[1]
             + q2.y * (float)h2[1] + q3.y * (float)h3[1];
        ac2 += q0.z * (float)h0[2] + q1.z * (float)h1[2]
             + q2.z * (float)h2[2] + q3.z * (float)h3[2];
        ac3 += q0.w * (float)h0[3] + q1.w * (float)h1[3]
             + q2.w * (float)h2[3] + q3.w * (float)h3[3];
    }
    for (; j < end; ++j) {
        int s = csr_src[j];
        float4 pv = p1[j];
        f16x4 hv = *(const f16x4*)&h1h[(size_t)s * 256 + lane * 4];
        den0 += pv.x; den1 += pv.y; den2 += pv.z; den3 += pv.w;
        ac0 += pv.x * (float)hv[0];
        ac1 += pv.y * (float)hv[1];
        ac2 += pv.z * (float)hv[2];
        ac3 += pv.w * (float)hv[3];
    }
    float r0 = ac0 / (den0 + 1e-16f) + b1[lane];
    float r1 = ac1 / (den1 + 1e-16f) + b1[64 + lane];
    float r2 = ac2 / (den2 + 1e-16f) + b1[128 + lane];
    float r3 = ac3 / (den3 + 1e-16f) + b1[192 + lane];
    f16* orow = &h1half[(size_t)n * 256];
    orow[lane]       = (f16)(r0 > 0.f ? r0 : 0.f);
    orow[64 + lane]  = (f16)(r1 > 0.f ? r1 : 0.f);
    orow[128 + lane] = (f16)(r2 > 0.f ? r2 : 0.f);
    orow[192 + lane] = (f16)(r3 > 0.f ? r3 : 0.f);
}

// Layer-2 aggregation (1 head, no relu): h2 = agg + b2, fp16 out (GEMM3 input)
__global__ __launch_bounds__(256)
void agg2_kernel(const int* __restrict__ offs, const int* __restrict__ csr_src,
                 const float* __restrict__ p2, const f16* __restrict__ h2linh,
                 const float* __restrict__ b2, f16* __restrict__ h2half) {
    int lane = threadIdx.x & 63;
    int n = blockIdx.x * 4 + (threadIdx.x >> 6);
    if (n >= NN) return;
    int beg = (n == 0) ? 0 : offs[n - 1];
    int end = offs[n];
    float den = 0.f, acc = 0.f;
    int j = beg;
    for (; j + 4 <= end; j += 4) {
        int s0 = csr_src[j + 0];
        int s1 = csr_src[j + 1];
        int s2 = csr_src[j + 2];
        int s3 = csr_src[j + 3];
        float q0 = p2[j + 0];
        float q1 = p2[j + 1];
        float q2 = p2[j + 2];
        float q3 = p2[j + 3];
        float v0 = (float)h2linh[(size_t)s0 * 64 + lane];
        float v1 = (float)h2linh[(size_t)s1 * 64 + lane];
        float v2 = (float)h2linh[(size_t)s2 * 64 + lane];
        float v3 = (float)h2linh[(size_t)s3 * 64 + lane];
        den += (q0 + q1) + (q2 + q3);
        acc += q0 * v0 + q1 * v1 + q2 * v2 + q3 * v3;
    }
    for (; j < end; ++j) {
        int s = csr_src[j];
        float p = p2[j];
        den += p;
        acc += p * (float)h2linh[(size_t)s * 64 + lane];
    }
    h2half[(size_t)n * 64 + lane] = (f16)(acc / (den + 1e-16f) + b2[lane]);
}

// ---------------------------------------------------------------------------
// Edge epilogue: z = relu(g_top[p] + g_bot[c] + bm1); out = z @ Wm2 + bm2
// 16 lanes per edge; gh is fp16 [n][128].
// ---------------------------------------------------------------------------

__global__ __launch_bounds__(256)
void edge_kernel(const int* __restrict__ ei, const f16* __restrict__ gh,
                 const float* __restrict__ bm1, const float* __restrict__ Wm2,
                 const float* __restrict__ bm2, float* __restrict__ out) {
    int l = threadIdx.x & 15;
    int eid = blockIdx.x * 16 + (threadIdx.x >> 4);
    if (eid >= EE) return;
    int p = ei[eid];
    int c = ei[EE + eid];
    f16x4 av = *(const f16x4*)&gh[(size_t)p * 128 + l * 4];
    f16x4 bv = *(const f16x4*)&gh[(size_t)c * 128 + 64 + l * 4];
    float4 bb = *(const float4*)&bm1[l * 4];
    float zx = (float)av[0] + (float)bv[0] + bb.x; zx = zx > 0.f ? zx : 0.f;
    float zy = (float)av[1] + (float)bv[1] + bb.y; zy = zy > 0.f ? zy : 0.f;
    float zz = (float)av[2] + (float)bv[2] + bb.z; zz = zz > 0.f ? zz : 0.f;
    float zw = (float)av[3] + (float)bv[3] + bb.w; zw = zw > 0.f ? zw : 0.f;
    float4 w01 = *(const float4*)&Wm2[l * 8];       // rows 4l, 4l+1
    float4 w23 = *(const float4*)&Wm2[l * 8 + 4];   // rows 4l+2, 4l+3
    float o0 = zx * w01.x + zy * w01.z + zz * w23.x + zw * w23.z;
    float o1 = zx * w01.y + zy * w01.w + zz * w23.y + zw * w23.w;
#pragma unroll
    for (int m = 1; m < 16; m <<= 1) {
        o0 += __shfl_xor(o0, m);
        o1 += __shfl_xor(o1, m);
    }
    if (l == 0)
        *(float2*)&out[(size_t)eid * 2] = make_float2(o0 + bm2[0], o1 + bm2[1]);
}

// ---------------------------------------------------------------------------

extern "C" void kernel_launch(void* const* d_in, const int* in_sizes, int n_in,
                              void* d_out, int out_size, void* d_ws, size_t ws_size,
                              hipStream_t stream) {
    const float* x      = (const float*)d_in[0];
    const int*   ei     = (const int*)d_in[1];
    const float* W1     = (const float*)d_in[2];
    const float* a_src1 = (const float*)d_in[3];
    const float* a_dst1 = (const float*)d_in[4];
    const float* b1     = (const float*)d_in[5];
    const float* W2     = (const float*)d_in[6];
    const float* a_src2 = (const float*)d_in[7];
    const float* a_dst2 = (const float*)d_in[8];
    const float* b2     = (const float*)d_in[9];
    const float* Wm1    = (const float*)d_in[10];
    const float* bm1    = (const float*)d_in[11];
    const float* Wm2    = (const float*)d_in[12];
    const float* bm2    = (const float*)d_in[13];
    float* out = (float*)d_out;

    char* ws = (char*)d_ws;
    size_t off = 0;
    auto alloc = [&](size_t bytes) -> void* {
        void* p = ws + off;
        off += (bytes + 255) & ~(size_t)255;
        return p;
    };
    int*    deg     = (int*)alloc((size_t)NN * 4);
    int*    offs    = (int*)alloc((size_t)NN * 4);
    int*    bsum    = (int*)alloc(64 * 4);
    int*    bpre    = (int*)alloc(64 * 4);
    int*    csr_src = (int*)alloc((size_t)ENE * 4);
    int*    csr_dst = (int*)alloc((size_t)ENE * 4);
    float*  ss1     = (float*)alloc((size_t)NN * 4 * 4);
    float*  sd1     = (float*)alloc((size_t)NN * 4 * 4);
    float*  ss2     = (float*)alloc((size_t)NN * 4);
    float*  sd2     = (float*)alloc((size_t)NN * 4);
    float4* p1      = (float4*)alloc((size_t)ENE * 16);
    float*  p2      = (float*)alloc((size_t)ENE * 4);
    f16*    xh      = (f16*)alloc((size_t)NN * 128 * 2);
    f16*    W1t     = (f16*)alloc((size_t)256 * 128 * 2);
    f16*    W2t     = (f16*)alloc((size_t)64 * 256 * 2);
    f16*    Wmt     = (f16*)alloc((size_t)128 * 64 * 2);
    f16*    h1h     = (f16*)alloc((size_t)NN * 256 * 2);   // permuted [n][c][h]
    f16*    h1half  = (f16*)alloc((size_t)NN * 256 * 2);   // [n][h*64+c]
    f16*    h2linh  = (f16*)alloc((size_t)NN * 64 * 2);
    f16*    h2half  = (f16*)alloc((size_t)NN * 64 * 2);
    f16*    gh      = (f16*)alloc((size_t)NN * 128 * 2);
    if (off > ws_size) return;   // insufficient workspace: leave output poisoned

    const int nbScan  = (NN + 1023) / 1024;        // 49
    const int gEdges  = (ENE + 255) / 256;         // 3321
    const int gNodes4 = (NN + 3) / 4;              // 12500
    const int gEdge16 = (EE + 15) / 16;            // 50000

    // Casts (independent of CSR)
    cast_x_kernel<<<(NN * 128 / 4 + 255) / 256, 256, 0, stream>>>((const float4*)x, xh);
    cast_w_kernel<<<(57344 + 255) / 256, 256, 0, stream>>>(W1, W2, Wm1, W1t, W2t, Wmt);

    // CSR build
    hipMemsetAsync(deg, 0, (size_t)NN * 4, stream);
    deg_kernel<<<gEdges, 256, 0, stream>>>(ei, deg);
    scan1_kernel<<<nbScan, 1024, 0, stream>>>(deg, offs, bsum);
    scan2_kernel<<<1, 64, 0, stream>>>(bsum, bpre, nbScan);
    scan3_kernel<<<(NN + 255) / 256, 256, 0, stream>>>(offs, bpre);
    scatter_kernel<<<gEdges, 256, 0, stream>>>(ei, offs, csr_src, csr_dst);

    // Layer 1: h1h = fp16( xh @ W1 ), permuted epilogue
    mfma_gemm<128, 256, 1, 4, 1><<<NN / 16, 256, 0, stream>>>(xh, W1t, h1h, NN);
    scores1_kernel<<<gNodes4, 256, 0, stream>>>(h1h, a_src1, a_dst1, ss1, sd1);
    p1_kernel<<<gEdges, 256, 0, stream>>>(csr_src, csr_dst, ss1, sd1, p1);
    agg1_kernel<<<gNodes4, 256, 0, stream>>>(offs, csr_src, p1, h1h, b1, h1half);

    // Layer 2
    mfma_gemm<256, 64, 4, 1, 0><<<(NN + 63) / 64, 256, 0, stream>>>(h1half, W2t, h2linh, NN);
    scores2_kernel<<<gNodes4, 256, 0, stream>>>(h2linh, a_src2, a_dst2, ss2, sd2);
    p2_kernel<<<gEdges, 256, 0, stream>>>(csr_src, csr_dst, ss2, sd2, p2);
    agg2_kernel<<<gNodes4, 256, 0, stream>>>(offs, csr_src, p2, h2linh, b2, h2half);

    // Edge MLP (factorized): gh = h2 @ [Wm1_top | Wm1_bot], per-edge epilogue
    mfma_gemm<64, 128, 2, 2, 0><<<(NN + 31) / 32, 256, 0, stream>>>(h2half, Wmt, gh, NN);
    edge_kernel<<<gEdge16, 256, 0, stream>>>(ei, gh, bm1, Wm2, bm2, out);
}

// Round 6
// 427.431 us; speedup vs baseline: 1.5309x; 1.0530x over previous
//
#include <hip/hip_runtime.h>
#include <hip/hip_fp16.h>

#define NN 50000
#define EE 800000
#define ENE (EE + NN)   // edges + self loops

typedef _Float16 f16;
typedef __attribute__((ext_vector_type(8))) _Float16 f16x8;
typedef __attribute__((ext_vector_type(4))) _Float16 f16x4;
typedef __attribute__((ext_vector_type(4))) float f32x4;

// ---------------------------------------------------------------------------
// CSR build: degree count -> exclusive scan -> scatter (bump allocator).
// After scatter, offs[n] = end of segment n; beg(n) = n ? offs[n-1] : 0.
// ---------------------------------------------------------------------------

__global__ __launch_bounds__(256)
void deg_kernel(const int* __restrict__ ei, int* __restrict__ deg) {
    int i = blockIdx.x * 256 + threadIdx.x;
    if (i >= ENE) return;
    int d = (i < EE) ? ei[EE + i] : (i - EE);   // dst row of edge_index
    atomicAdd(&deg[d], 1);
}

__global__ __launch_bounds__(1024)
void scan1_kernel(const int* __restrict__ deg, int* __restrict__ offs,
                  int* __restrict__ bsum) {
    __shared__ int s[1024];
    int t = threadIdx.x;
    int i = blockIdx.x * 1024 + t;
    int v = (i < NN) ? deg[i] : 0;
    s[t] = v;
    __syncthreads();
    for (int off = 1; off < 1024; off <<= 1) {
        int a = (t >= off) ? s[t - off] : 0;
        __syncthreads();
        s[t] += a;
        __syncthreads();
    }
    if (i < NN) offs[i] = s[t] - v;   // exclusive
    if (t == 1023) bsum[blockIdx.x] = s[1023];
}

__global__ __launch_bounds__(64)
void scan2_kernel(const int* __restrict__ bsum, int* __restrict__ bpre, int nb) {
    if (threadIdx.x == 0) {
        int run = 0;
        for (int b = 0; b < nb; ++b) { bpre[b] = run; run += bsum[b]; }
    }
}

__global__ __launch_bounds__(256)
void scan3_kernel(int* __restrict__ offs, const int* __restrict__ bpre) {
    int i = blockIdx.x * 256 + threadIdx.x;
    if (i >= NN) return;
    offs[i] += bpre[i >> 10];
}

__global__ __launch_bounds__(256)
void scatter_kernel(const int* __restrict__ ei, int* __restrict__ offs,
                    int* __restrict__ csr_src, int* __restrict__ csr_dst) {
    int i = blockIdx.x * 256 + threadIdx.x;
    if (i >= ENE) return;
    int d, s;
    if (i < EE) { s = ei[i]; d = ei[EE + i]; }
    else        { s = i - EE; d = i - EE; }
    int p = atomicAdd(&offs[d], 1);
    csr_src[p] = s;
    csr_dst[p] = d;
}

// ---------------------------------------------------------------------------
// fp32 weights -> transposed fp16 copies (MFMA B-fragments = contiguous 16B).
// ---------------------------------------------------------------------------

__global__ __launch_bounds__(256)
void cast_w_kernel(const float* __restrict__ W1, const float* __restrict__ W2,
                   const float* __restrict__ Wm1, f16* __restrict__ W1t,
                   f16* __restrict__ W2t, f16* __restrict__ Wmt) {
    int idx = blockIdx.x * 256 + threadIdx.x;
    if (idx < 32768) {                       // W1t[j*128+k] = W1[k*256+j]
        int j = idx >> 7, k = idx & 127;
        W1t[idx] = (f16)W1[k * 256 + j];
    } else if (idx < 49152) {                // W2t[j*256+k] = W2[k*64+j]
        int i = idx - 32768;
        int j = i >> 8, k = i & 255;
        W2t[i] = (f16)W2[k * 64 + j];
    } else if (idx < 57344) {                // Wmt[j*64+k]
        int i = idx - 49152;
        int j = i >> 6, k = i & 63;
        float v = (j < 64) ? Wm1[k * 64 + j] : Wm1[(64 + k) * 64 + (j - 64)];
        Wmt[i] = (f16)v;
    }
}

// ---------------------------------------------------------------------------
// MFMA fp16 GEMM: Yh[n, NOUT] = A[n, K] @ Bt^T   (Bt is [NOUT][K] fp16)
// 4 waves/block; wave (wr,wc) computes 16 rows x 64 cols via 4x
// v_mfma_f32_16x16x32_f16 per k-step, register-direct fragments.
// PERM=1: permuted [n][c(64)][h(4)] output layout.
// AF32=1: A is fp32, converted in-register (kills separate cast kernel).
// SCORES=1: fused layer-1 attention scores (needs PERM=1, NWR=1).
// SCORES=2: fused layer-2 scores (needs NOUT=64).
// ---------------------------------------------------------------------------

template<int K, int NOUT, int NWR, int NWC, int PERM, int AF32, int SCORES>
__global__ __launch_bounds__(256)
void mfma_gemm(const void* __restrict__ Avoid, const f16* __restrict__ Bt,
               f16* __restrict__ Yh, const float* __restrict__ a_src,
               const float* __restrict__ a_dst, float* __restrict__ ss,
               float* __restrict__ sd, int nrows) {
    constexpr int BROWS = NWR * 16;
    constexpr int LDP = NOUT + 8;            // halves per LDS row (16B pad)
    __shared__ f16 lds[BROWS * LDP];
    const int tid = threadIdx.x;
    const int wid = tid >> 6, lane = tid & 63;
    const int wr = wid / NWC, wc = wid % NWC;
    const int lm = lane & 15, lk = lane >> 4;      // lk in 0..3
    const int row0 = blockIdx.x * BROWS + wr * 16;
    const int col0 = wc * 64;

    const float* A32 = (const float*)Avoid;
    const f16*   A16 = (const f16*)Avoid;

    int arow = row0 + lm;
    if (arow >= nrows) arow = nrows - 1;           // clamp (partial last block)

    f32x4 acc[4] = {};
#pragma unroll
    for (int ks = 0; ks < K / 32; ++ks) {
        f16x8 af;
        if (AF32) {
            float4 v0 = *(const float4*)&A32[(size_t)arow * K + ks * 32 + lk * 8];
            float4 v1 = *(const float4*)&A32[(size_t)arow * K + ks * 32 + lk * 8 + 4];
            af = f16x8{(f16)v0.x, (f16)v0.y, (f16)v0.z, (f16)v0.w,
                       (f16)v1.x, (f16)v1.y, (f16)v1.z, (f16)v1.w};
        } else {
            af = *(const f16x8*)(A16 + (size_t)arow * K + ks * 32 + lk * 8);
        }
#pragma unroll
        for (int ct = 0; ct < 4; ++ct) {
            const f16* bptr = Bt + (size_t)(col0 + ct * 16 + lm) * K + ks * 32 + lk * 8;
            f16x8 bf = *(const f16x8*)bptr;
            acc[ct] = __builtin_amdgcn_mfma_f32_16x16x32_f16(af, bf, acc[ct], 0, 0, 0);
        }
    }

    // C/D frag: col = lane&15, row = (lane>>4)*4 + r  [m89 layout]
#pragma unroll
    for (int ct = 0; ct < 4; ++ct) {
#pragma unroll
        for (int r = 0; r < 4; ++r) {
            int lrow = wr * 16 + lk * 4 + r;       // local row in block
            int j = col0 + ct * 16 + lm;           // global col
            int jj = PERM ? ((j & 63) * 4 + (j >> 6)) : j;
            lds[lrow * LDP + jj] = (f16)acc[ct][r];
        }
    }
    __syncthreads();

    constexpr int CHUNKS = NOUT / 8;               // 16B chunks per row
    for (int idx = tid; idx < BROWS * CHUNKS; idx += 256) {
        int lrow = idx / CHUNKS, ch = idx % CHUNKS;
        int grow = blockIdx.x * BROWS + lrow;
        if (grow < nrows) {
            f16x8 v = *(const f16x8*)&lds[lrow * LDP + ch * 8];
            *(f16x8*)&Yh[(size_t)grow * NOUT + ch * 8] = v;
        }
    }

    if (SCORES == 1) {
        // layer-1: ss[n][h] = sum_c h[n,h,c]*a_src[h,c]; lds is [16][c*4+h].
        // wave w -> rows 4w..4w+3 (lane>>4), 16 lanes/row, 4 c's per lane.
        int rloc = wid * 4 + (lane >> 4);
        int ci = lane & 15;
        float ps[4] = {}, pd[4] = {};
#pragma unroll
        for (int cc = 0; cc < 4; ++cc) {
            int c = ci + cc * 16;
            f16x4 hv = *(const f16x4*)&lds[rloc * LDP + c * 4];
#pragma unroll
            for (int h = 0; h < 4; ++h) {
                float f = (float)hv[h];
                ps[h] += f * a_src[h * 64 + c];
                pd[h] += f * a_dst[h * 64 + c];
            }
        }
#pragma unroll
        for (int m = 1; m < 16; m <<= 1) {
#pragma unroll
            for (int h = 0; h < 4; ++h) {
                ps[h] += __shfl_xor(ps[h], m);
                pd[h] += __shfl_xor(pd[h], m);
            }
        }
        if (ci == 0) {
            int grow = blockIdx.x * BROWS + rloc;
            if (grow < nrows) {
                *(float4*)&ss[grow * 4] = make_float4(ps[0], ps[1], ps[2], ps[3]);
                *(float4*)&sd[grow * 4] = make_float4(pd[0], pd[1], pd[2], pd[3]);
            }
        }
    } else if (SCORES == 2) {
        // layer-2: ss[n] = sum_c h2[n,c]*a_src[c]; 4 lanes/row, 16 c's each.
        int rloc = wid * 16 + (lane >> 2);
        int cg = lane & 3;
        float ps = 0.f, pd = 0.f;
#pragma unroll
        for (int b = 0; b < 2; ++b) {
            f16x8 hv = *(const f16x8*)&lds[rloc * LDP + cg * 16 + b * 8];
#pragma unroll
            for (int u = 0; u < 8; ++u) {
                int c = cg * 16 + b * 8 + u;
                float f = (float)hv[u];
                ps += f * a_src[c];
                pd += f * a_dst[c];
            }
        }
        ps += __shfl_xor(ps, 1); ps += __shfl_xor(ps, 2);
        pd += __shfl_xor(pd, 1); pd += __shfl_xor(pd, 2);
        if (cg == 0) {
            int grow = blockIdx.x * BROWS + rloc;
            if (grow < nrows) { ss[grow] = ps; sd[grow] = pd; }
        }
    }
}

// ---------------------------------------------------------------------------
// Per-edge (CSR-slot-ordered) unnormalized softmax weights.
// ---------------------------------------------------------------------------

__global__ __launch_bounds__(256)
void p1_kernel(const int* __restrict__ csr_src, const int* __restrict__ csr_dst,
               const float* __restrict__ ss, const float* __restrict__ sd,
               float4* __restrict__ p1) {
    int j = blockIdx.x * 256 + threadIdx.x;
    if (j >= ENE) return;
    int s = csr_src[j], d = csr_dst[j];
    float4 a = *(const float4*)&ss[s * 4];
    float4 b = *(const float4*)&sd[d * 4];
    float e0 = a.x + b.x; e0 = e0 > 0.f ? e0 : 0.2f * e0;
    float e1 = a.y + b.y; e1 = e1 > 0.f ? e1 : 0.2f * e1;
    float e2 = a.z + b.z; e2 = e2 > 0.f ? e2 : 0.2f * e2;
    float e3 = a.w + b.w; e3 = e3 > 0.f ? e3 : 0.2f * e3;
    p1[j] = make_float4(__expf(e0), __expf(e1), __expf(e2), __expf(e3));
}

__global__ __launch_bounds__(256)
void p2_kernel(const int* __restrict__ csr_src, const int* __restrict__ csr_dst,
               const float* __restrict__ ss, const float* __restrict__ sd,
               float* __restrict__ p2) {
    int j = blockIdx.x * 256 + threadIdx.x;
    if (j >= ENE) return;
    float e = ss[csr_src[j]] + sd[csr_dst[j]];
    e = e > 0.f ? e : 0.2f * e;
    p2[j] = __expf(e);
}

// ---------------------------------------------------------------------------
// Layer-1 aggregation: wave per dst node, lane = channel, fp16 gather.
// 8x manual unroll: 8 independent row-gathers in flight per wave.
// ---------------------------------------------------------------------------

__global__ __launch_bounds__(256)
void agg1_kernel(const int* __restrict__ offs, const int* __restrict__ csr_src,
                 const float4* __restrict__ p1, const f16* __restrict__ h1h,
                 const float* __restrict__ b1, f16* __restrict__ h1half) {
    int lane = threadIdx.x & 63;
    int n = blockIdx.x * 4 + (threadIdx.x >> 6);
    if (n >= NN) return;
    int beg = (n == 0) ? 0 : offs[n - 1];
    int end = offs[n];
    float den0 = 0.f, den1 = 0.f, den2 = 0.f, den3 = 0.f;
    float ac0 = 0.f, ac1 = 0.f, ac2 = 0.f, ac3 = 0.f;
    int j = beg;
    for (; j + 8 <= end; j += 8) {
        int s[8];
#pragma unroll
        for (int u = 0; u < 8; ++u) s[u] = csr_src[j + u];
        float4 q[8];
#pragma unroll
        for (int u = 0; u < 8; ++u) q[u] = p1[j + u];
        f16x4 hv[8];
#pragma unroll
        for (int u = 0; u < 8; ++u)
            hv[u] = *(const f16x4*)&h1h[(size_t)s[u] * 256 + lane * 4];
#pragma unroll
        for (int u = 0; u < 8; ++u) {
            den0 += q[u].x; den1 += q[u].y; den2 += q[u].z; den3 += q[u].w;
            ac0 += q[u].x * (float)hv[u][0];
            ac1 += q[u].y * (float)hv[u][1];
            ac2 += q[u].z * (float)hv[u][2];
            ac3 += q[u].w * (float)hv[u][3];
        }
    }
    for (; j < end; ++j) {
        int s = csr_src[j];
        float4 pv = p1[j];
        f16x4 hv = *(const f16x4*)&h1h[(size_t)s * 256 + lane * 4];
        den0 += pv.x; den1 += pv.y; den2 += pv.z; den3 += pv.w;
        ac0 += pv.x * (float)hv[0];
        ac1 += pv.y * (float)hv[1];
        ac2 += pv.z * (float)hv[2];
        ac3 += pv.w * (float)hv[3];
    }
    float r0 = ac0 / (den0 + 1e-16f) + b1[lane];
    float r1 = ac1 / (den1 + 1e-16f) + b1[64 + lane];
    float r2 = ac2 / (den2 + 1e-16f) + b1[128 + lane];
    float r3 = ac3 / (den3 + 1e-16f) + b1[192 + lane];
    f16* orow = &h1half[(size_t)n * 256];
    orow[lane]       = (f16)(r0 > 0.f ? r0 : 0.f);
    orow[64 + lane]  = (f16)(r1 > 0.f ? r1 : 0.f);
    orow[128 + lane] = (f16)(r2 > 0.f ? r2 : 0.f);
    orow[192 + lane] = (f16)(r3 > 0.f ? r3 : 0.f);
}

// Layer-2 aggregation (1 head, no relu): h2 = agg + b2, fp16 out (GEMM3 input)
__global__ __launch_bounds__(256)
void agg2_kernel(const int* __restrict__ offs, const int* __restrict__ csr_src,
                 const float* __restrict__ p2, const f16* __restrict__ h2linh,
                 const float* __restrict__ b2, f16* __restrict__ h2half) {
    int lane = threadIdx.x & 63;
    int n = blockIdx.x * 4 + (threadIdx.x >> 6);
    if (n >= NN) return;
    int beg = (n == 0) ? 0 : offs[n - 1];
    int end = offs[n];
    float den = 0.f, acc = 0.f;
    int j = beg;
    for (; j + 8 <= end; j += 8) {
        int s[8];
#pragma unroll
        for (int u = 0; u < 8; ++u) s[u] = csr_src[j + u];
        float q[8];
#pragma unroll
        for (int u = 0; u < 8; ++u) q[u] = p2[j + u];
        float v[8];
#pragma unroll
        for (int u = 0; u < 8; ++u)
            v[u] = (float)h2linh[(size_t)s[u] * 64 + lane];
#pragma unroll
        for (int u = 0; u < 8; ++u) {
            den += q[u];
            acc += q[u] * v[u];
        }
    }
    for (; j < end; ++j) {
        int s = csr_src[j];
        float p = p2[j];
        den += p;
        acc += p * (float)h2linh[(size_t)s * 64 + lane];
    }
    h2half[(size_t)n * 64 + lane] = (f16)(acc / (den + 1e-16f) + b2[lane]);
}

// ---------------------------------------------------------------------------
// Edge epilogue: z = relu(g_top[p] + g_bot[c] + bm1); out = z @ Wm2 + bm2
// 16 lanes per edge; gh is fp16 [n][128].
// ---------------------------------------------------------------------------

__global__ __launch_bounds__(256)
void edge_kernel(const int* __restrict__ ei, const f16* __restrict__ gh,
                 const float* __restrict__ bm1, const float* __restrict__ Wm2,
                 const float* __restrict__ bm2, float* __restrict__ out) {
    int l = threadIdx.x & 15;
    int eid = blockIdx.x * 16 + (threadIdx.x >> 4);
    if (eid >= EE) return;
    int p = ei[eid];
    int c = ei[EE + eid];
    f16x4 av = *(const f16x4*)&gh[(size_t)p * 128 + l * 4];
    f16x4 bv = *(const f16x4*)&gh[(size_t)c * 128 + 64 + l * 4];
    float4 bb = *(const float4*)&bm1[l * 4];
    float zx = (float)av[0] + (float)bv[0] + bb.x; zx = zx > 0.f ? zx : 0.f;
    float zy = (float)av[1] + (float)bv[1] + bb.y; zy = zy > 0.f ? zy : 0.f;
    float zz = (float)av[2] + (float)bv[2] + bb.z; zz = zz > 0.f ? zz : 0.f;
    float zw = (float)av[3] + (float)bv[3] + bb.w; zw = zw > 0.f ? zw : 0.f;
    float4 w01 = *(const float4*)&Wm2[l * 8];       // rows 4l, 4l+1
    float4 w23 = *(const float4*)&Wm2[l * 8 + 4];   // rows 4l+2, 4l+3
    float o0 = zx * w01.x + zy * w01.z + zz * w23.x + zw * w23.z;
    float o1 = zx * w01.y + zy * w01.w + zz * w23.y + zw * w23.w;
#pragma unroll
    for (int m = 1; m < 16; m <<= 1) {
        o0 += __shfl_xor(o0, m);
        o1 += __shfl_xor(o1, m);
    }
    if (l == 0)
        *(float2*)&out[(size_t)eid * 2] = make_float2(o0 + bm2[0], o1 + bm2[1]);
}

// ---------------------------------------------------------------------------

extern "C" void kernel_launch(void* const* d_in, const int* in_sizes, int n_in,
                              void* d_out, int out_size, void* d_ws, size_t ws_size,
                              hipStream_t stream) {
    const float* x      = (const float*)d_in[0];
    const int*   ei     = (const int*)d_in[1];
    const float* W1     = (const float*)d_in[2];
    const float* a_src1 = (const float*)d_in[3];
    const float* a_dst1 = (const float*)d_in[4];
    const float* b1     = (const float*)d_in[5];
    const float* W2     = (const float*)d_in[6];
    const float* a_src2 = (const float*)d_in[7];
    const float* a_dst2 = (const float*)d_in[8];
    const float* b2     = (const float*)d_in[9];
    const float* Wm1    = (const float*)d_in[10];
    const float* bm1    = (const float*)d_in[11];
    const float* Wm2    = (const float*)d_in[12];
    const float* bm2    = (const float*)d_in[13];
    float* out = (float*)d_out;

    char* ws = (char*)d_ws;
    size_t off = 0;
    auto alloc = [&](size_t bytes) -> void* {
        void* p = ws + off;
        off += (bytes + 255) & ~(size_t)255;
        return p;
    };
    int*    deg     = (int*)alloc((size_t)NN * 4);
    int*    offs    = (int*)alloc((size_t)NN * 4);
    int*    bsum    = (int*)alloc(64 * 4);
    int*    bpre    = (int*)alloc(64 * 4);
    int*    csr_src = (int*)alloc((size_t)ENE * 4);
    int*    csr_dst = (int*)alloc((size_t)ENE * 4);
    float*  ss1     = (float*)alloc((size_t)NN * 4 * 4);
    float*  sd1     = (float*)alloc((size_t)NN * 4 * 4);
    float*  ss2     = (float*)alloc((size_t)NN * 4);
    float*  sd2     = (float*)alloc((size_t)NN * 4);
    float4* p1      = (float4*)alloc((size_t)ENE * 16);
    float*  p2      = (float*)alloc((size_t)ENE * 4);
    f16*    W1t     = (f16*)alloc((size_t)256 * 128 * 2);
    f16*    W2t     = (f16*)alloc((size_t)64 * 256 * 2);
    f16*    Wmt     = (f16*)alloc((size_t)128 * 64 * 2);
    f16*    h1h     = (f16*)alloc((size_t)NN * 256 * 2);   // permuted [n][c][h]
    f16*    h1half  = (f16*)alloc((size_t)NN * 256 * 2);   // [n][h*64+c]
    f16*    h2linh  = (f16*)alloc((size_t)NN * 64 * 2);
    f16*    h2half  = (f16*)alloc((size_t)NN * 64 * 2);
    f16*    gh      = (f16*)alloc((size_t)NN * 128 * 2);
    if (off > ws_size) return;   // insufficient workspace: leave output poisoned

    const int nbScan  = (NN + 1023) / 1024;        // 49
    const int gEdges  = (ENE + 255) / 256;         // 3321
    const int gNodes4 = (NN + 3) / 4;              // 12500
    const int gEdge16 = (EE + 15) / 16;            // 50000

    // Weight casts (independent of CSR)
    cast_w_kernel<<<(57344 + 255) / 256, 256, 0, stream>>>(W1, W2, Wm1, W1t, W2t, Wmt);

    // CSR build
    hipMemsetAsync(deg, 0, (size_t)NN * 4, stream);
    deg_kernel<<<gEdges, 256, 0, stream>>>(ei, deg);
    scan1_kernel<<<nbScan, 1024, 0, stream>>>(deg, offs, bsum);
    scan2_kernel<<<1, 64, 0, stream>>>(bsum, bpre, nbScan);
    scan3_kernel<<<(NN + 255) / 256, 256, 0, stream>>>(offs, bpre);
    scatter_kernel<<<gEdges, 256, 0, stream>>>(ei, offs, csr_src, csr_dst);

    // Layer 1: h1h = fp16( x @ W1 ), permuted epilogue + fused scores
    mfma_gemm<128, 256, 1, 4, 1, 1, 1><<<NN / 16, 256, 0, stream>>>(
        x, W1t, h1h, a_src1, a_dst1, ss1, sd1, NN);
    p1_kernel<<<gEdges, 256, 0, stream>>>(csr_src, csr_dst, ss1, sd1, p1);
    agg1_kernel<<<gNodes4, 256, 0, stream>>>(offs, csr_src, p1, h1h, b1, h1half);

    // Layer 2: h2lin = h1 @ W2 (+ fused scores)
    mfma_gemm<256, 64, 4, 1, 0, 0, 2><<<(NN + 63) / 64, 256, 0, stream>>>(
        h1half, W2t, h2linh, a_src2, a_dst2, ss2, sd2, NN);
    p2_kernel<<<gEdges, 256, 0, stream>>>(csr_src, csr_dst, ss2, sd2, p2);
    agg2_kernel<<<gNodes4, 256, 0, stream>>>(offs, csr_src, p2, h2linh, b2, h2half);

    // Edge MLP (factorized): gh = h2 @ [Wm1_top | Wm1_bot], per-edge epilogue
    mfma_gemm<64, 128, 2, 2, 0, 0, 0><<<(NN + 31) / 32, 256, 0, stream>>>(
        h2half, Wmt, gh, nullptr, nullptr, nullptr, nullptr, NN);
    edge_kernel<<<gEdge16, 256, 0, stream>>>(ei, gh, bm1, Wm2, bm2, out);
}